// Round 2
// baseline (2596.313 us; speedup 1.0000x reference)
//
#include <hip/hip_runtime.h>
#include <hip/hip_bf16.h>

// Problem constants
#define B_    2
#define S_    2048
#define DIM_  512
#define H_    8
#define HD_   64
#define TOUT_ 1536   // 2*QK + DIM

typedef unsigned short ushort_t;
typedef __attribute__((ext_vector_type(8))) __bf16 bf16x8;
typedef __attribute__((ext_vector_type(4))) float floatx4;

#define AS_GLB __attribute__((address_space(1)))
#define AS_LDS __attribute__((address_space(3)))

// ---------- dtype helpers ----------
__device__ __forceinline__ float bf2f(unsigned int u) { return __uint_as_float(u << 16); }
__device__ __forceinline__ unsigned short f2bfu(float f) {
    unsigned u = __float_as_uint(f);
    unsigned r = (u + 0x7fffu + ((u >> 16) & 1u)) >> 16;
    return (unsigned short)r;
}

__device__ __forceinline__ float4 ldf4(const float* p) { return *reinterpret_cast<const float4*>(p); }
__device__ __forceinline__ float4 ldf4(const __hip_bfloat16* p) {
    uint2 u = *reinterpret_cast<const uint2*>(p);
    float4 r;
    r.x = bf2f(u.x & 0xffffu);
    r.y = bf2f(u.x >> 16);
    r.z = bf2f(u.y & 0xffffu);
    r.w = bf2f(u.y >> 16);
    return r;
}
__device__ __forceinline__ float ldf1(const float* p) { return *p; }
__device__ __forceinline__ float ldf1(const __hip_bfloat16* p) {
    return bf2f((unsigned int)*reinterpret_cast<const unsigned short*>(p));
}
__device__ __forceinline__ void stf1(float* p, float v) { *p = v; }
__device__ __forceinline__ void stf1(__hip_bfloat16* p, float v) { *p = __float2bfloat16(v); }

// ---------- dtype detection ----------
// flags[0]: 0 = float tensors are fp32, 1 = bf16
// flags[1]: mask class: 0=u8 bool, 1=int32, 2=bf16, 3=fp32
__global__ void tmha_detect(const unsigned char* xb, const unsigned char* mb, int* flags) {
    __shared__ int s_exp, s_bf, s_f, s_u8;
    int tid = threadIdx.x;
    if (tid == 0) { s_exp = 0; s_bf = 0; s_f = 0; s_u8 = 0; }
    __syncthreads();
    int cexp = 0, cbf = 0, cf = 0, cu8 = 0;
    for (int i = tid; i < 1024; i += 256) {
        unsigned char v = xb[4 * i + 1];
        if ((v >= 0x20 && v <= 0x43) || (v >= 0xA0 && v <= 0xC3)) cexp++;
    }
    for (int i = tid; i < 4096; i += 256) {
        unsigned char v = mb[i];
        if (v == 0x3F || v == 0x80) {
            cf++;
            if ((i & 3) == 1) cbf++;
        } else if (v != 0 && (i & 3) != 0) {
            cu8++;
        }
    }
    atomicAdd(&s_exp, cexp); atomicAdd(&s_bf, cbf);
    atomicAdd(&s_f, cf);     atomicAdd(&s_u8, cu8);
    __syncthreads();
    if (tid == 0) {
        flags[0] = (s_exp > 640) ? 1 : 0;
        int mcls;
        if (s_bf > 0)      mcls = 2;
        else if (s_f > 0)  mcls = 3;
        else if (s_u8 > 0) mcls = 0;
        else               mcls = 1;
        flags[1] = mcls;
    }
}

__global__ void tmha_decode_mask(const unsigned char* mb, const int* flags, int* wm) {
    int i = blockIdx.x * 256 + threadIdx.x;
    if (i >= B_ * S_) return;
    int cls = flags[1];
    int v;
    if (cls == 0)      v = (mb[i] != 0);
    else if (cls == 1) v = (reinterpret_cast<const int*>(mb)[i] != 0);
    else if (cls == 2) v = ((reinterpret_cast<const unsigned short*>(mb)[i] & 0x7fffu) != 0);
    else               v = ((reinterpret_cast<const unsigned int*>(mb)[i] & 0x7fffffffu) != 0);
    wm[i] = v;
}

// ==================================================================
// MFMA GEMM: C[M,N] = A[M,KA] @ B[N,K]^T   (bf16 inputs, fp32 acc)
// KA == K normally; KA == 2K -> doubled-K (A = [hi|lo] split, B col = k % K).
// 128x128 tile, BK=64, 256 threads = 4 waves in 2x2, each wave 64x64 (4x4 MFMA accs).
// ==================================================================
template <typename CT, int M, int N, int K, int KA>
__global__ __launch_bounds__(256) void mfma_gemm_bt(const ushort_t* __restrict__ A,
                                                    const ushort_t* __restrict__ Bm,
                                                    CT* __restrict__ C,
                                                    const int* __restrict__ flags) {
    if (flags[0] != 1) return;   // bf16 path only
    __shared__ __align__(16) ushort_t As[128 * 64];
    __shared__ __align__(16) ushort_t Bs[128 * 64];
    int tid = threadIdx.x;
    int lane = tid & 63;
    int w = tid >> 6;
    int wm = w >> 1, wn = w & 1;
    int bx = blockIdx.x;   // over N/128
    int by = blockIdx.y;   // over M/128

    floatx4 acc[4][4];
#pragma unroll
    for (int i = 0; i < 4; i++)
#pragma unroll
        for (int j = 0; j < 4; j++) acc[i][j] = (floatx4){0.f, 0.f, 0.f, 0.f};

    int srow = lane >> 3;          // 0..7 within an 8-row staging slab
    int scol = (lane & 7) * 8;     // 0..56, 8 bf16 = 16 B per lane
    int quad = lane >> 4;
    int mrow = lane & 15;

    for (int k0 = 0; k0 < KA; k0 += 64) {
        int kb = k0 % K;
#pragma unroll
        for (int t = 0; t < 4; t++) {
            int slab = w * 4 + t;              // 0..15 -> 8 rows each
            int rr = slab * 8 + srow;
            const ushort_t* ga = A  + (size_t)(by * 128 + rr) * KA + k0 + scol;
            const ushort_t* gb = Bm + (size_t)(bx * 128 + rr) * K  + kb + scol;
            __builtin_amdgcn_global_load_lds((const AS_GLB unsigned int*)ga,
                                             (AS_LDS unsigned int*)&As[slab * 512], 16, 0, 0);
            __builtin_amdgcn_global_load_lds((const AS_GLB unsigned int*)gb,
                                             (AS_LDS unsigned int*)&Bs[slab * 512], 16, 0, 0);
        }
        __syncthreads();
#pragma unroll
        for (int ks = 0; ks < 64; ks += 32) {
            bf16x8 af[4], bf[4];
#pragma unroll
            for (int i = 0; i < 4; i++)
                af[i] = *reinterpret_cast<const bf16x8*>(&As[(wm * 64 + i * 16 + mrow) * 64 + ks + quad * 8]);
#pragma unroll
            for (int j = 0; j < 4; j++)
                bf[j] = *reinterpret_cast<const bf16x8*>(&Bs[(wn * 64 + j * 16 + mrow) * 64 + ks + quad * 8]);
#pragma unroll
            for (int i = 0; i < 4; i++)
#pragma unroll
                for (int j = 0; j < 4; j++)
                    acc[i][j] = __builtin_amdgcn_mfma_f32_16x16x32_bf16(af[i], bf[j], acc[i][j], 0, 0, 0);
        }
        __syncthreads();
    }

    // epilogue: C/D layout col = lane&15, row = (lane>>4)*4 + reg
    int col0 = bx * 128 + wn * 64 + mrow;
    int row0 = by * 128 + wm * 64 + quad * 4;
#pragma unroll
    for (int i = 0; i < 4; i++)
#pragma unroll
        for (int j = 0; j < 4; j++)
#pragma unroll
            for (int r = 0; r < 4; r++) {
                int row = row0 + i * 16 + r;
                int col = col0 + j * 16;
                stf1(C + (size_t)row * N + col, acc[i][j][r]);
            }
}

// ---------- fp32-fallback t = x @ W_trans^T ----------
template <typename T>
__global__ __launch_bounds__(256) void tmha_gemm1(const T* __restrict__ x,
                                                  const T* __restrict__ W,
                                                  float* __restrict__ t,
                                                  const int* __restrict__ flags, int tag) {
    if (flags[0] != tag) return;
    __shared__ float xs[DIM_];
    int bid = blockIdx.x;
    int row = bid / 6;
    int seg = bid % 6;
    int o = seg * 256 + threadIdx.x;
    const T* xrow = x + (size_t)row * DIM_;
    for (int e = threadIdx.x; e < DIM_; e += 256) xs[e] = ldf1(xrow + e);
    __syncthreads();
    const T* wr = W + (size_t)o * DIM_;
    float acc = 0.f;
    for (int d = 0; d < DIM_; d += 4) {
        float4 wv = ldf4(wr + d);
        acc += xs[d] * wv.x + xs[d + 1] * wv.y + xs[d + 2] * wv.z + xs[d + 3] * wv.w;
    }
    t[(size_t)row * TOUT_ + o] = acc;
}

// ---------- rotate q,k where mask ----------
template <typename T>
__global__ __launch_bounds__(256) void tmha_rot(const T* __restrict__ rot,
                                                const int* __restrict__ wm,
                                                float* __restrict__ t,
                                                const int* __restrict__ flags, int tag) {
    if (flags[0] != tag) return;
    int row = blockIdx.x;
    if (!wm[row]) return;
    __shared__ float rotT[64 * 65];
    __shared__ float qk[1024];
    const T* rp = rot + (size_t)row * 4096;
    for (int e = threadIdx.x * 4; e < 4096; e += 1024) {
        float4 v = ldf4(rp + e);
        int i = e >> 6, j = e & 63;
        rotT[(j + 0) * 65 + i] = v.x;
        rotT[(j + 1) * 65 + i] = v.y;
        rotT[(j + 2) * 65 + i] = v.z;
        rotT[(j + 3) * 65 + i] = v.w;
    }
    float* trow = t + (size_t)row * TOUT_;
    for (int e = threadIdx.x; e < 1024; e += 256) qk[e] = trow[e];
    __syncthreads();
    float res[4];
    for (int r = 0; r < 4; r++) {
        int u = threadIdx.x + 256 * r;
        int i = u & 63;
        int base = u & ~63;
        float acc = 0.f;
        for (int j = 0; j < 64; j++) acc += rotT[j * 65 + i] * qk[base + j];
        res[r] = acc;
    }
    __syncthreads();
    for (int r = 0; r < 4; r++) {
        int u = threadIdx.x + 256 * r;
        trow[u] = res[r];
    }
}

// ---------- taylor attention (flash-style, fp32) ----------
__global__ __launch_bounds__(256) void tmha_attn(const float* __restrict__ t,
                                                 const int* __restrict__ wm,
                                                 float* __restrict__ attn_f,
                                                 ushort_t* __restrict__ attn2,
                                                 const int* __restrict__ flags) {
    __shared__ float Kt[64 * 65];
    __shared__ float Vt[64 * 64];
    __shared__ float qs[16 * 64];
    __shared__ float wbuf[16 * 64];
    int tid = threadIdx.x;
    int lane = tid & 63;
    int w = tid >> 6;
    int bid = blockIdx.x;
    int b = bid >> 10;
    int rem = bid & 1023;
    int h = rem >> 7;
    int qt = rem & 127;
    int rowb = b * S_;

    for (int r = 0; r < 4; r++) {
        int qrow = qt * 16 + w * 4 + r;
        qs[(w * 4 + r) * 64 + lane] = t[(size_t)(rowb + qrow) * TOUT_ + h * 64 + lane];
    }

    float outacc[4] = {0.f, 0.f, 0.f, 0.f};
    float dacc[4]   = {0.f, 0.f, 0.f, 0.f};

    for (int kt2 = 0; kt2 < S_; kt2 += 64) {
        __syncthreads();
        for (int e4 = tid; e4 < 1024; e4 += 256) {
            int kk = e4 >> 4;
            int d4 = (e4 & 15) * 4;
            const float* kbase = &t[(size_t)(rowb + kt2 + kk) * TOUT_ + 512 + h * 64 + d4];
            const float* vbase = &t[(size_t)(rowb + kt2 + kk) * TOUT_ + 1024 + h * 64 + d4];
            float4 kv = *reinterpret_cast<const float4*>(kbase);
            float4 vv = *reinterpret_cast<const float4*>(vbase);
            Kt[(d4 + 0) * 65 + kk] = kv.x;
            Kt[(d4 + 1) * 65 + kk] = kv.y;
            Kt[(d4 + 2) * 65 + kk] = kv.z;
            Kt[(d4 + 3) * 65 + kk] = kv.w;
            *reinterpret_cast<float4*>(&Vt[kk * 64 + d4]) = vv;
        }
        __syncthreads();

        int key = kt2 + lane;
        int m = wm[b * S_ + key];
        float s0 = 0.f, s1 = 0.f, s2 = 0.f, s3 = 0.f;
        for (int d = 0; d < 64; d++) {
            float kv = Kt[d * 65 + lane];
            s0 += qs[(w * 4 + 0) * 64 + d] * kv;
            s1 += qs[(w * 4 + 1) * 64 + d] * kv;
            s2 += qs[(w * 4 + 2) * 64 + d] * kv;
            s3 += qs[(w * 4 + 3) * 64 + d] * kv;
        }
        float sc[4] = {s0, s1, s2, s3};
        for (int r = 0; r < 4; r++) {
            float s = sc[r] * 0.125f;
            float wg = 1.0f + s + 0.5f * s * s;
            wg = m ? wg : 0.0f;
            wbuf[(w * 4 + r) * 64 + lane] = wg;
            dacc[r] += wg;
        }
        for (int k = 0; k < 64; k++) {
            float vv = Vt[k * 64 + lane];
            outacc[0] += wbuf[(w * 4 + 0) * 64 + k] * vv;
            outacc[1] += wbuf[(w * 4 + 1) * 64 + k] * vv;
            outacc[2] += wbuf[(w * 4 + 2) * 64 + k] * vv;
            outacc[3] += wbuf[(w * 4 + 3) * 64 + k] * vv;
        }
    }

    int isbf = flags[0];
    for (int r = 0; r < 4; r++) {
        float d = dacc[r];
        for (int off = 32; off > 0; off >>= 1) d += __shfl_down(d, off, 64);
        d = __shfl(d, 0, 64);
        int qrow = qt * 16 + w * 4 + r;
        float v = outacc[r] / d;
        if (isbf) {
            // hi/lo bf16 split for the MFMA gemm2 (a = hi + lo, fp32-accurate)
            unsigned short hu = f2bfu(v);
            float hf = bf2f(hu);
            unsigned short lu = f2bfu(v - hf);
            size_t base = (size_t)(rowb + qrow) * 1024 + h * 64 + lane;
            attn2[base] = hu;
            attn2[base + 512] = lu;
        } else {
            attn_f[(size_t)(rowb + qrow) * DIM_ + h * 64 + lane] = v;
        }
    }
}

// ---------- fp32-fallback out = attn @ W_o^T ----------
template <typename T>
__global__ __launch_bounds__(256) void tmha_gemm2(const float* __restrict__ attn,
                                                  const T* __restrict__ Wo,
                                                  T* __restrict__ out,
                                                  const int* __restrict__ flags, int tag) {
    if (flags[0] != tag) return;
    __shared__ float arow[DIM_];
    int row = blockIdx.x >> 1;
    int seg = blockIdx.x & 1;
    int dcol = seg * 256 + threadIdx.x;
    for (int e = threadIdx.x; e < DIM_; e += 256) arow[e] = attn[(size_t)row * DIM_ + e];
    __syncthreads();
    const T* wr = Wo + (size_t)dcol * DIM_;
    float acc = 0.f;
    for (int e = 0; e < DIM_; e += 4) {
        float4 wv = ldf4(wr + e);
        acc += arow[e] * wv.x + arow[e + 1] * wv.y + arow[e + 2] * wv.z + arow[e + 3] * wv.w;
    }
    stf1(out + (size_t)row * DIM_ + dcol, acc);
}

extern "C" void kernel_launch(void* const* d_in, const int* in_sizes, int n_in,
                              void* d_out, int out_size, void* d_ws, size_t ws_size,
                              hipStream_t stream) {
    (void)in_sizes; (void)n_in; (void)out_size; (void)ws_size;
    const void* x    = d_in[0];
    const void* mask = d_in[1];
    const void* rot  = d_in[2];
    const void* Wt   = d_in[3];
    const void* Wo   = d_in[4];

    char* ws = (char*)d_ws;
    int* flags      = (int*)ws;                                        // 64 B
    int* wmask      = (int*)(ws + 64);                                 // 16 KB
    float* t        = (float*)(ws + 64 + 16384);                       // 25,165,824 B
    float* attn_f   = (float*)(ws + 64 + 16384 + 25165824);            // 8,388,608 B
    ushort_t* attn2 = (ushort_t*)(ws + 64 + 16384 + 25165824 + 8388608); // 8,388,608 B

    tmha_detect<<<1, 256, 0, stream>>>((const unsigned char*)x, (const unsigned char*)mask, flags);
    tmha_decode_mask<<<16, 256, 0, stream>>>((const unsigned char*)mask, flags, wmask);

    // gemm1: bf16 MFMA path + fp32 VALU fallback
    {
        dim3 grid(TOUT_ / 128, (B_ * S_) / 128);
        mfma_gemm_bt<float, B_ * S_, TOUT_, DIM_, DIM_><<<grid, 256, 0, stream>>>(
            (const ushort_t*)x, (const ushort_t*)Wt, t, flags);
    }
    tmha_gemm1<float><<<B_ * S_ * 6, 256, 0, stream>>>(
        (const float*)x, (const float*)Wt, t, flags, 0);

    tmha_rot<__hip_bfloat16><<<B_ * S_, 256, 0, stream>>>(
        (const __hip_bfloat16*)rot, wmask, t, flags, 1);
    tmha_rot<float><<<B_ * S_, 256, 0, stream>>>(
        (const float*)rot, wmask, t, flags, 0);

    tmha_attn<<<B_ * H_ * (S_ / 16), 256, 0, stream>>>(t, wmask, attn_f, attn2, flags);

    // gemm2: bf16 MFMA (doubled-K hi/lo) + fp32 VALU fallback
    {
        dim3 grid(DIM_ / 128, (B_ * S_) / 128);
        mfma_gemm_bt<__hip_bfloat16, B_ * S_, DIM_, DIM_, 2 * DIM_><<<grid, 256, 0, stream>>>(
            attn2, (const ushort_t*)Wo, (__hip_bfloat16*)d_out, flags);
    }
    tmha_gemm2<float><<<B_ * S_ * 2, 256, 0, stream>>>(
        attn_f, (const float*)Wo, (float*)d_out, flags, 0);
}

// Round 3
// 873.904 us; speedup vs baseline: 2.9709x; 2.9709x over previous
//
#include <hip/hip_runtime.h>
#include <hip/hip_bf16.h>

// Problem constants
#define B_    2
#define S_    2048
#define DIM_  512
#define H_    8
#define HD_   64
#define TOUT_ 1536   // 2*QK + DIM
#define ROWS_ (B_ * S_)   // 4096

typedef unsigned short ushort_t;
typedef __attribute__((ext_vector_type(8))) __bf16 bf16x8;
typedef __attribute__((ext_vector_type(4))) float floatx4;

#define AS_GLB __attribute__((address_space(1)))
#define AS_LDS __attribute__((address_space(3)))

// ---------- numeric helpers ----------
__device__ __forceinline__ float bf2f(unsigned int u) { return __uint_as_float(u << 16); }
__device__ __forceinline__ unsigned short f2bfu(float f) {
    unsigned u = __float_as_uint(f);
    unsigned r = (u + 0x7fffu + ((u >> 16) & 1u)) >> 16;
    return (unsigned short)r;
}

// ---------- mask classification (confirmed working in R1/R2; kept verbatim) ----------
// flags[1]: mask class: 0=u8 bool, 1=int32, 2=bf16, 3=fp32
__global__ void tmha_detect(const unsigned char* xb, const unsigned char* mb, int* flags) {
    __shared__ int s_exp, s_bf, s_f, s_u8;
    int tid = threadIdx.x;
    if (tid == 0) { s_exp = 0; s_bf = 0; s_f = 0; s_u8 = 0; }
    __syncthreads();
    int cexp = 0, cbf = 0, cf = 0, cu8 = 0;
    for (int i = tid; i < 1024; i += 256) {
        unsigned char v = xb[4 * i + 1];
        if ((v >= 0x20 && v <= 0x43) || (v >= 0xA0 && v <= 0xC3)) cexp++;
    }
    for (int i = tid; i < 4096; i += 256) {
        unsigned char v = mb[i];
        if (v == 0x3F || v == 0x80) {
            cf++;
            if ((i & 3) == 1) cbf++;
        } else if (v != 0 && (i & 3) != 0) {
            cu8++;
        }
    }
    atomicAdd(&s_exp, cexp); atomicAdd(&s_bf, cbf);
    atomicAdd(&s_f, cf);     atomicAdd(&s_u8, cu8);
    __syncthreads();
    if (tid == 0) {
        flags[0] = (s_exp > 640) ? 1 : 0;   // R1/R2 measured: 0 (fp32 tensors)
        int mcls;
        if (s_bf > 0)      mcls = 2;
        else if (s_f > 0)  mcls = 3;
        else if (s_u8 > 0) mcls = 0;
        else               mcls = 1;
        flags[1] = mcls;
    }
}

__global__ void tmha_decode_mask(const unsigned char* mb, const int* flags, int* wm) {
    int i = blockIdx.x * 256 + threadIdx.x;
    if (i >= ROWS_) return;
    int cls = flags[1];
    int v;
    if (cls == 0)      v = (mb[i] != 0);
    else if (cls == 1) v = (reinterpret_cast<const int*>(mb)[i] != 0);
    else if (cls == 2) v = ((reinterpret_cast<const unsigned short*>(mb)[i] & 0x7fffu) != 0);
    else               v = ((reinterpret_cast<const unsigned int*>(mb)[i] & 0x7fffffffu) != 0);
    wm[i] = v;
}

// ---------- fp32 -> bf16 hi/lo split prep ----------
// A-side layout (x, attention output): [h | l | h]   (3*512 cols)
// B-side layout (weights):             [h | h | l]
// sum over 1536: ah*bh + al*bh + ah*bl  (drops al*bl ~ 2^-18 rel)
__global__ __launch_bounds__(256) void prep_split_a(const float* __restrict__ src,
                                                    ushort_t* __restrict__ dst, int n) {
    int i = blockIdx.x * 256 + threadIdx.x;
    if (i >= n) return;
    float v = src[i];
    unsigned short hu = f2bfu(v);
    float hf = bf2f(hu);
    unsigned short lu = f2bfu(v - hf);
    int r = i >> 9, c = i & 511;
    size_t b = (size_t)r * 1536 + c;
    dst[b] = hu; dst[b + 512] = lu; dst[b + 1024] = hu;
}

__global__ __launch_bounds__(256) void prep_split_b(const float* __restrict__ src,
                                                    ushort_t* __restrict__ dst, int n) {
    int i = blockIdx.x * 256 + threadIdx.x;
    if (i >= n) return;
    float v = src[i];
    unsigned short hu = f2bfu(v);
    float hf = bf2f(hu);
    unsigned short lu = f2bfu(v - hf);
    int r = i >> 9, c = i & 511;
    size_t b = (size_t)r * 1536 + c;
    dst[b] = hu; dst[b + 512] = hu; dst[b + 1024] = lu;
}

// ==================================================================
// MFMA GEMM: C[M,N] = A[M,K] @ B[N,K]^T  (bf16 in, fp32 acc/out)
// 128x128 tile, BK=64, 256 threads = 4 waves (2x2), each wave 64x64.
// ==================================================================
template <int M, int N, int K>
__global__ __launch_bounds__(256) void mfma_gemm_bt(const ushort_t* __restrict__ A,
                                                    const ushort_t* __restrict__ Bm,
                                                    float* __restrict__ C) {
    __shared__ __align__(16) ushort_t As[128 * 64];
    __shared__ __align__(16) ushort_t Bs[128 * 64];
    int tid = threadIdx.x;
    int lane = tid & 63;
    int w = tid >> 6;
    int wm = w >> 1, wn = w & 1;
    int bx = blockIdx.x;   // over N/128
    int by = blockIdx.y;   // over M/128

    floatx4 acc[4][4];
#pragma unroll
    for (int i = 0; i < 4; i++)
#pragma unroll
        for (int j = 0; j < 4; j++) acc[i][j] = (floatx4){0.f, 0.f, 0.f, 0.f};

    int srow = lane >> 3;          // 0..7 within an 8-row staging slab
    int scol = (lane & 7) * 8;     // 8 bf16 = 16 B per lane
    int quad = lane >> 4;
    int mrow = lane & 15;

    for (int k0 = 0; k0 < K; k0 += 64) {
#pragma unroll
        for (int t = 0; t < 4; t++) {
            int slab = w * 4 + t;              // 16 slabs x 8 rows = 128 rows
            int rr = slab * 8 + srow;
            const ushort_t* ga = A  + (size_t)(by * 128 + rr) * K + k0 + scol;
            const ushort_t* gb = Bm + (size_t)(bx * 128 + rr) * K + k0 + scol;
            __builtin_amdgcn_global_load_lds((const AS_GLB unsigned int*)ga,
                                             (AS_LDS unsigned int*)&As[slab * 512], 16, 0, 0);
            __builtin_amdgcn_global_load_lds((const AS_GLB unsigned int*)gb,
                                             (AS_LDS unsigned int*)&Bs[slab * 512], 16, 0, 0);
        }
        __syncthreads();   // compiler emits vmcnt(0) drain before barrier -> LDS valid
#pragma unroll
        for (int ks = 0; ks < 64; ks += 32) {
            bf16x8 af[4], bf[4];
#pragma unroll
            for (int i = 0; i < 4; i++)
                af[i] = *reinterpret_cast<const bf16x8*>(&As[(wm * 64 + i * 16 + mrow) * 64 + ks + quad * 8]);
#pragma unroll
            for (int j = 0; j < 4; j++)
                bf[j] = *reinterpret_cast<const bf16x8*>(&Bs[(wn * 64 + j * 16 + mrow) * 64 + ks + quad * 8]);
#pragma unroll
            for (int i = 0; i < 4; i++)
#pragma unroll
                for (int j = 0; j < 4; j++)
                    acc[i][j] = __builtin_amdgcn_mfma_f32_16x16x32_bf16(af[i], bf[j], acc[i][j], 0, 0, 0);
        }
        __syncthreads();
    }

    // C/D layout: col = lane&15, row = (lane>>4)*4 + reg   [m89/m91 verified]
    int col0 = bx * 128 + wn * 64 + mrow;
    int row0 = by * 128 + wm * 64 + quad * 4;
#pragma unroll
    for (int i = 0; i < 4; i++)
#pragma unroll
        for (int j = 0; j < 4; j++)
#pragma unroll
            for (int r = 0; r < 4; r++) {
                int row = row0 + i * 16 + r;
                int col = col0 + j * 16;
                C[(size_t)row * N + col] = acc[i][j][r];
            }
}

// ---------- rotate q,k where mask (fp32, proven) ----------
__global__ __launch_bounds__(256) void tmha_rot(const float* __restrict__ rot,
                                                const int* __restrict__ wm,
                                                float* __restrict__ t) {
    int row = blockIdx.x;                 // b*S + s
    if (!wm[row]) return;
    __shared__ float rotT[64 * 65];       // rotT[j*65+i] = rot[i][j]
    __shared__ float qk[1024];
    const float* rp = rot + (size_t)row * 4096;
    for (int e = threadIdx.x * 4; e < 4096; e += 1024) {
        float4 v = *reinterpret_cast<const float4*>(rp + e);
        int i = e >> 6, j = e & 63;
        rotT[(j + 0) * 65 + i] = v.x;
        rotT[(j + 1) * 65 + i] = v.y;
        rotT[(j + 2) * 65 + i] = v.z;
        rotT[(j + 3) * 65 + i] = v.w;
    }
    float* trow = t + (size_t)row * TOUT_;
    for (int e = threadIdx.x; e < 1024; e += 256) qk[e] = trow[e];
    __syncthreads();
    float res[4];
    for (int r = 0; r < 4; r++) {
        int u = threadIdx.x + 256 * r;    // [sel(1)|h(3)|i(6)]
        int i = u & 63;
        int base = u & ~63;               // sel*512 + h*64
        float acc = 0.f;
        for (int j = 0; j < 64; j++) acc += rotT[j * 65 + i] * qk[base + j];
        res[r] = acc;
    }
    __syncthreads();
    for (int r = 0; r < 4; r++) {
        int u = threadIdx.x + 256 * r;
        trow[u] = res[r];
    }
}

// ---------- taylor attention (flash-style, fp32; epilogue emits split) ----------
__global__ __launch_bounds__(256) void tmha_attn(const float* __restrict__ t,
                                                 const int* __restrict__ wm,
                                                 ushort_t* __restrict__ attnA2) {
    __shared__ float Kt[64 * 65];
    __shared__ float Vt[64 * 64];
    __shared__ float qs[16 * 64];
    __shared__ float wbuf[16 * 64];
    int tid = threadIdx.x;
    int lane = tid & 63;
    int w = tid >> 6;
    int bid = blockIdx.x;
    int b = bid >> 10;                    // H*(S/16) = 1024 blocks per batch
    int rem = bid & 1023;
    int h = rem >> 7;
    int qt = rem & 127;
    int rowb = b * S_;

    for (int r = 0; r < 4; r++) {
        int qrow = qt * 16 + w * 4 + r;
        qs[(w * 4 + r) * 64 + lane] = t[(size_t)(rowb + qrow) * TOUT_ + h * 64 + lane];
    }

    float outacc[4] = {0.f, 0.f, 0.f, 0.f};
    float dacc[4]   = {0.f, 0.f, 0.f, 0.f};

    for (int kt2 = 0; kt2 < S_; kt2 += 64) {
        __syncthreads();
        for (int e4 = tid; e4 < 1024; e4 += 256) {
            int kk = e4 >> 4;
            int d4 = (e4 & 15) * 4;
            const float* kbase = &t[(size_t)(rowb + kt2 + kk) * TOUT_ + 512 + h * 64 + d4];
            const float* vbase = &t[(size_t)(rowb + kt2 + kk) * TOUT_ + 1024 + h * 64 + d4];
            float4 kv = *reinterpret_cast<const float4*>(kbase);
            float4 vv = *reinterpret_cast<const float4*>(vbase);
            Kt[(d4 + 0) * 65 + kk] = kv.x;
            Kt[(d4 + 1) * 65 + kk] = kv.y;
            Kt[(d4 + 2) * 65 + kk] = kv.z;
            Kt[(d4 + 3) * 65 + kk] = kv.w;
            *reinterpret_cast<float4*>(&Vt[kk * 64 + d4]) = vv;
        }
        __syncthreads();

        int key = kt2 + lane;
        int m = wm[b * S_ + key];
        float s0 = 0.f, s1 = 0.f, s2 = 0.f, s3 = 0.f;
        for (int d = 0; d < 64; d++) {
            float kv = Kt[d * 65 + lane];
            s0 += qs[(w * 4 + 0) * 64 + d] * kv;
            s1 += qs[(w * 4 + 1) * 64 + d] * kv;
            s2 += qs[(w * 4 + 2) * 64 + d] * kv;
            s3 += qs[(w * 4 + 3) * 64 + d] * kv;
        }
        float sc[4] = {s0, s1, s2, s3};
        for (int r = 0; r < 4; r++) {
            float s = sc[r] * 0.125f;
            float wg = 1.0f + s + 0.5f * s * s;
            wg = m ? wg : 0.0f;
            wbuf[(w * 4 + r) * 64 + lane] = wg;
            dacc[r] += wg;
        }
        for (int k = 0; k < 64; k++) {
            float vv = Vt[k * 64 + lane];
            outacc[0] += wbuf[(w * 4 + 0) * 64 + k] * vv;
            outacc[1] += wbuf[(w * 4 + 1) * 64 + k] * vv;
            outacc[2] += wbuf[(w * 4 + 2) * 64 + k] * vv;
            outacc[3] += wbuf[(w * 4 + 3) * 64 + k] * vv;
        }
    }

    for (int r = 0; r < 4; r++) {
        float d = dacc[r];
        for (int off = 32; off > 0; off >>= 1) d += __shfl_down(d, off, 64);
        d = __shfl(d, 0, 64);
        int qrow = qt * 16 + w * 4 + r;
        float v = outacc[r] / d;
        unsigned short hu = f2bfu(v);
        float hf = bf2f(hu);
        unsigned short lu = f2bfu(v - hf);
        size_t base = (size_t)(rowb + qrow) * 1536 + h * 64 + lane;
        attnA2[base] = hu;            // [h | l | h] A-side split layout
        attnA2[base + 512] = lu;
        attnA2[base + 1024] = hu;
    }
}

extern "C" void kernel_launch(void* const* d_in, const int* in_sizes, int n_in,
                              void* d_out, int out_size, void* d_ws, size_t ws_size,
                              hipStream_t stream) {
    (void)in_sizes; (void)n_in; (void)out_size; (void)ws_size;
    const float* x    = (const float*)d_in[0];
    const void*  mask = d_in[1];
    const float* rot  = (const float*)d_in[2];
    const float* Wt   = (const float*)d_in[3];
    const float* Wo   = (const float*)d_in[4];

    char* ws = (char*)d_ws;
    int* flags      = (int*)ws;                              // 64 B
    int* wmask      = (int*)(ws + 64);                       // 16 KB
    float* t        = (float*)(ws + 32768);                  // 4096*1536*4 = 25,165,824 B
    ushort_t* A2    = (ushort_t*)(ws + 32768 + 25165824);    // 4096*1536*2 = 12,582,912 B (x-split, later attn-split)
    ushort_t* B2t   = (ushort_t*)(ws + 32768 + 25165824 + 12582912); // 1536*1536*2 = 4,718,592 B (later Wo-split)
    ushort_t* B2o   = B2t;                                   // reuse after gemm1 (stream-ordered)

    tmha_detect<<<1, 256, 0, stream>>>((const unsigned char*)x, (const unsigned char*)mask, flags);
    tmha_decode_mask<<<16, 256, 0, stream>>>((const unsigned char*)mask, flags, wmask);

    // ---- gemm1: t = x @ W_trans^T via split-bf16 MFMA ----
    prep_split_a<<<(ROWS_ * DIM_) / 256, 256, 0, stream>>>(x, A2, ROWS_ * DIM_);
    prep_split_b<<<(TOUT_ * DIM_) / 256, 256, 0, stream>>>(Wt, B2t, TOUT_ * DIM_);
    {
        dim3 grid(TOUT_ / 128, ROWS_ / 128);
        mfma_gemm_bt<ROWS_, TOUT_, 1536><<<grid, 256, 0, stream>>>(A2, B2t, t);
    }

    tmha_rot<<<ROWS_, 256, 0, stream>>>(rot, wmask, t);

    tmha_attn<<<B_ * H_ * (S_ / 16), 256, 0, stream>>>(t, wmask, A2);  // A2 now attn split

    // ---- gemm2: out = attn @ W_o^T via split-bf16 MFMA ----
    prep_split_b<<<(DIM_ * DIM_) / 256, 256, 0, stream>>>(Wo, B2o, DIM_ * DIM_);
    {
        dim3 grid(DIM_ / 128, ROWS_ / 128);
        mfma_gemm_bt<ROWS_, DIM_, 1536><<<grid, 256, 0, stream>>>(A2, B2o, (float*)d_out);
    }
}

// Round 4
// 256.964 us; speedup vs baseline: 10.1038x; 3.4009x over previous
//
#include <hip/hip_runtime.h>
#include <hip/hip_bf16.h>

// Problem constants
#define B_    2
#define S_    2048
#define DIM_  512
#define H_    8
#define HD_   64
#define TOUT_ 1536   // 2*QK + DIM
#define ROWS_ (B_ * S_)   // 4096

typedef unsigned short ushort_t;
typedef __attribute__((ext_vector_type(8))) __bf16 bf16x8;
typedef __attribute__((ext_vector_type(4))) float floatx4;

#define AS_GLB __attribute__((address_space(1)))
#define AS_LDS __attribute__((address_space(3)))

// ---------- numeric helpers ----------
__device__ __forceinline__ float bf2f(unsigned int u) { return __uint_as_float(u << 16); }
__device__ __forceinline__ unsigned short f2bfu(float f) {
    unsigned u = __float_as_uint(f);
    unsigned r = (u + 0x7fffu + ((u >> 16) & 1u)) >> 16;
    return (unsigned short)r;
}

// ---------- mask classification (proven R1-R3) ----------
__global__ void tmha_detect(const unsigned char* xb, const unsigned char* mb, int* flags) {
    __shared__ int s_bf, s_f, s_u8;
    int tid = threadIdx.x;
    if (tid == 0) { s_bf = 0; s_f = 0; s_u8 = 0; }
    __syncthreads();
    int cbf = 0, cf = 0, cu8 = 0;
    for (int i = tid; i < 4096; i += 256) {
        unsigned char v = mb[i];
        if (v == 0x3F || v == 0x80) {
            cf++;
            if ((i & 3) == 1) cbf++;
        } else if (v != 0 && (i & 3) != 0) {
            cu8++;
        }
    }
    atomicAdd(&s_bf, cbf); atomicAdd(&s_f, cf); atomicAdd(&s_u8, cu8);
    __syncthreads();
    if (tid == 0) {
        int mcls;
        if (s_bf > 0)      mcls = 2;
        else if (s_f > 0)  mcls = 3;
        else if (s_u8 > 0) mcls = 0;
        else               mcls = 1;
        flags[1] = mcls;
    }
    (void)xb;
}

__global__ void tmha_decode_mask(const unsigned char* mb, const int* flags, int* wm) {
    int i = blockIdx.x * 256 + threadIdx.x;
    if (i >= ROWS_) return;
    int cls = flags[1];
    int v;
    if (cls == 0)      v = (mb[i] != 0);
    else if (cls == 1) v = (reinterpret_cast<const int*>(mb)[i] != 0);
    else if (cls == 2) v = ((reinterpret_cast<const unsigned short*>(mb)[i] & 0x7fffu) != 0);
    else               v = ((reinterpret_cast<const unsigned int*>(mb)[i] & 0x7fffffffu) != 0);
    wm[i] = v;
}

// ---------- fp32 -> bf16 hi/lo split prep (proven R3) ----------
__global__ __launch_bounds__(256) void prep_split_a(const float* __restrict__ src,
                                                    ushort_t* __restrict__ dst, int n) {
    int i = blockIdx.x * 256 + threadIdx.x;
    if (i >= n) return;
    float v = src[i];
    unsigned short hu = f2bfu(v);
    float hf = bf2f(hu);
    unsigned short lu = f2bfu(v - hf);
    int r = i >> 9, c = i & 511;
    size_t b = (size_t)r * 1536 + c;
    dst[b] = hu; dst[b + 512] = lu; dst[b + 1024] = hu;
}

__global__ __launch_bounds__(256) void prep_split_b(const float* __restrict__ src,
                                                    ushort_t* __restrict__ dst, int n) {
    int i = blockIdx.x * 256 + threadIdx.x;
    if (i >= n) return;
    float v = src[i];
    unsigned short hu = f2bfu(v);
    float hf = bf2f(hu);
    unsigned short lu = f2bfu(v - hf);
    int r = i >> 9, c = i & 511;
    size_t b = (size_t)r * 1536 + c;
    dst[b] = hu; dst[b + 512] = hu; dst[b + 1024] = lu;
}

// ==================================================================
// MFMA GEMM (proven R3): C[M,N] = A[M,K] @ B[N,K]^T
// ==================================================================
template <int M, int N, int K>
__global__ __launch_bounds__(256) void mfma_gemm_bt(const ushort_t* __restrict__ A,
                                                    const ushort_t* __restrict__ Bm,
                                                    float* __restrict__ C) {
    __shared__ __align__(16) ushort_t As[128 * 64];
    __shared__ __align__(16) ushort_t Bs[128 * 64];
    int tid = threadIdx.x;
    int lane = tid & 63;
    int w = tid >> 6;
    int wm = w >> 1, wn = w & 1;
    int bx = blockIdx.x;
    int by = blockIdx.y;

    floatx4 acc[4][4];
#pragma unroll
    for (int i = 0; i < 4; i++)
#pragma unroll
        for (int j = 0; j < 4; j++) acc[i][j] = (floatx4){0.f, 0.f, 0.f, 0.f};

    int srow = lane >> 3;
    int scol = (lane & 7) * 8;
    int quad = lane >> 4;
    int mrow = lane & 15;

    for (int k0 = 0; k0 < K; k0 += 64) {
#pragma unroll
        for (int t = 0; t < 4; t++) {
            int slab = w * 4 + t;
            int rr = slab * 8 + srow;
            const ushort_t* ga = A  + (size_t)(by * 128 + rr) * K + k0 + scol;
            const ushort_t* gb = Bm + (size_t)(bx * 128 + rr) * K + k0 + scol;
            __builtin_amdgcn_global_load_lds((const AS_GLB unsigned int*)ga,
                                             (AS_LDS unsigned int*)&As[slab * 512], 16, 0, 0);
            __builtin_amdgcn_global_load_lds((const AS_GLB unsigned int*)gb,
                                             (AS_LDS unsigned int*)&Bs[slab * 512], 16, 0, 0);
        }
        __syncthreads();
#pragma unroll
        for (int ks = 0; ks < 64; ks += 32) {
            bf16x8 af[4], bf[4];
#pragma unroll
            for (int i = 0; i < 4; i++)
                af[i] = *reinterpret_cast<const bf16x8*>(&As[(wm * 64 + i * 16 + mrow) * 64 + ks + quad * 8]);
#pragma unroll
            for (int j = 0; j < 4; j++)
                bf[j] = *reinterpret_cast<const bf16x8*>(&Bs[(wn * 64 + j * 16 + mrow) * 64 + ks + quad * 8]);
#pragma unroll
            for (int i = 0; i < 4; i++)
#pragma unroll
                for (int j = 0; j < 4; j++)
                    acc[i][j] = __builtin_amdgcn_mfma_f32_16x16x32_bf16(af[i], bf[j], acc[i][j], 0, 0, 0);
        }
        __syncthreads();
    }

    int col0 = bx * 128 + wn * 64 + mrow;
    int row0 = by * 128 + wm * 64 + quad * 4;
#pragma unroll
    for (int i = 0; i < 4; i++)
#pragma unroll
        for (int j = 0; j < 4; j++)
#pragma unroll
            for (int r = 0; r < 4; r++)
                C[(size_t)(row0 + i * 16 + r) * N + col0 + j * 16] = acc[i][j][r];
}

// ---------- rotate q,k where mask (fp32, proven) ----------
__global__ __launch_bounds__(256) void tmha_rot(const float* __restrict__ rot,
                                                const int* __restrict__ wm,
                                                float* __restrict__ t) {
    int row = blockIdx.x;
    if (!wm[row]) return;
    __shared__ float rotT[64 * 65];
    __shared__ float qk[1024];
    const float* rp = rot + (size_t)row * 4096;
    for (int e = threadIdx.x * 4; e < 4096; e += 1024) {
        float4 v = *reinterpret_cast<const float4*>(rp + e);
        int i = e >> 6, j = e & 63;
        rotT[(j + 0) * 65 + i] = v.x;
        rotT[(j + 1) * 65 + i] = v.y;
        rotT[(j + 2) * 65 + i] = v.z;
        rotT[(j + 3) * 65 + i] = v.w;
    }
    float* trow = t + (size_t)row * TOUT_;
    for (int e = threadIdx.x; e < 1024; e += 256) qk[e] = trow[e];
    __syncthreads();
    float res[4];
    for (int r = 0; r < 4; r++) {
        int u = threadIdx.x + 256 * r;
        int i = u & 63;
        int base = u & ~63;
        float acc = 0.f;
        for (int j = 0; j < 64; j++) acc += rotT[j * 65 + i] * qk[base + j];
        res[r] = acc;
    }
    __syncthreads();
    for (int r = 0; r < 4; r++) {
        int u = threadIdx.x + 256 * r;
        trow[u] = res[r];
    }
}

// ---------- prep: t(fp32, post-rot) -> Qb/Kb bf16 [bh][s][64] ----------
__global__ __launch_bounds__(256) void prep_qk(const float* __restrict__ t,
                                               ushort_t* __restrict__ Qb,
                                               ushort_t* __restrict__ Kb) {
    int row = blockIdx.x;              // b*2048 + s
    int tid = threadIdx.x;
    int col = tid * 4;                 // 0..1020 (q:0-511, k:512-1023)
    float4 v = *reinterpret_cast<const float4*>(t + (size_t)row * TOUT_ + col);
    int isK = col >= 512;
    int c = col & 511;
    int h = c >> 6, d = c & 63;
    int b = row >> 11, s = row & 2047;
    ushort_t* dst = (isK ? Kb : Qb) + ((size_t)(b * 8 + h) * 2048 + s) * 64 + d;
    ushort_t o[4] = {f2bfu(v.x), f2bfu(v.y), f2bfu(v.z), f2bfu(v.w)};
    *reinterpret_cast<uint2*>(dst) = *reinterpret_cast<uint2*>(o);
}

// ---------- prep: V^T bf16 [bh][65][2048]; masked keys zeroed; row 64 = mask ----------
__global__ __launch_bounds__(256) void prep_vt(const float* __restrict__ t,
                                               const int* __restrict__ wm,
                                               ushort_t* __restrict__ VtG) {
    __shared__ float tile[64][65];
    __shared__ float mrow[64];
    int st = blockIdx.x;   // 0..31 (64-key tile)
    int bh = blockIdx.y;   // 0..15
    int b = bh >> 3, h = bh & 7;
    int tid = threadIdx.x;
    if (tid < 64) mrow[tid] = wm[b * 2048 + st * 64 + tid] ? 1.0f : 0.0f;
#pragma unroll
    for (int i = 0; i < 4; i++) {
        int q = i * 256 + tid;         // 0..1023 float4s
        int r = q >> 4, c4 = (q & 15) * 4;
        float4 v = *reinterpret_cast<const float4*>(
            t + (size_t)(b * 2048 + st * 64 + r) * TOUT_ + 1024 + h * 64 + c4);
        tile[r][c4] = v.x; tile[r][c4 + 1] = v.y; tile[r][c4 + 2] = v.z; tile[r][c4 + 3] = v.w;
    }
    __syncthreads();
#pragma unroll
    for (int i = 0; i < 8; i++) {
        int e = i * 256 + tid;         // 0..2047 (u32 pairs)
        int d = e >> 5, sl = (e & 31) * 2;
        float v0 = tile[sl][d] * mrow[sl];
        float v1 = tile[sl + 1][d] * mrow[sl + 1];
        unsigned int u = (unsigned)f2bfu(v0) | ((unsigned)f2bfu(v1) << 16);
        *reinterpret_cast<unsigned int*>(VtG + ((size_t)bh * 65 + d) * 2048 + st * 64 + sl) = u;
    }
    if (tid < 32) {
        int sl = tid * 2;
        unsigned m0 = mrow[sl]     != 0.f ? 0x3F80u : 0u;
        unsigned m1 = mrow[sl + 1] != 0.f ? 0x3F80u : 0u;
        *reinterpret_cast<unsigned int*>(VtG + ((size_t)bh * 65 + 64) * 2048 + st * 64 + sl) = m0 | (m1 << 16);
    }
}

// ==================================================================
// MFMA flash taylor-attention.
// Block: (qt 64-row Q tile, h, b). 256 thr = 4 waves, wave wv owns q rows wv*16..+16.
// K-loop tiles of 128 keys. XOR-swizzled LDS (2-way max on all accesses).
// Denominator via ones-column (Vt row 64 = mask); mask folded into V (cols zeroed).
// Epilogue: normalize, emit hi/lo split A2 for gemm2.
// ==================================================================
__global__ __launch_bounds__(256) void tmha_attn_mfma(const ushort_t* __restrict__ Qb,
                                                      const ushort_t* __restrict__ Kb,
                                                      const ushort_t* __restrict__ VtG,
                                                      ushort_t* __restrict__ attnA2) {
    __shared__ __align__(16) ushort_t Ks[1024 * 8];   // 128 keys x 8 chunks (16 KB)
    __shared__ __align__(16) ushort_t Vs[1280 * 8];   // 80 dims x 16 chunks (20 KB)
    __shared__ __align__(16) ushort_t Ps[1024 * 8];   // 64 q x 16 chunks (16 KB)
    int tid = threadIdx.x;
    int lane = tid & 63;
    int wv = tid >> 6;
    int lm = lane & 15;
    int quad = lane >> 4;
    int qt = blockIdx.x;
    int h = blockIdx.y;
    int b = blockIdx.z;
    int bh = b * 8 + h;

    // zero Vs rows 65..79 (chunks 1040..1279) once
    for (int i = tid; i < 960; i += 256)
        reinterpret_cast<unsigned int*>(&Vs[1040 * 8])[i] = 0u;

    // Q fragments in registers (A-operand): lane m=lm, dims kc*32 + quad*8..+8
    bf16x8 qf[2];
    {
        const ushort_t* qp = Qb + ((size_t)bh * 2048 + qt * 64 + wv * 16 + lm) * 64 + quad * 8;
        qf[0] = *reinterpret_cast<const bf16x8*>(qp);
        qf[1] = *reinterpret_cast<const bf16x8*>(qp + 32);
    }

    floatx4 oacc[5];
#pragma unroll
    for (int j = 0; j < 5; j++) oacc[j] = (floatx4){0.f, 0.f, 0.f, 0.f};

    for (int kt = 0; kt < S_; kt += 128) {
        // ---- stage K tile: 128 rows x 8 chunks, swizzle pos = row*8 + (c ^ (row&7)) ----
#pragma unroll
        for (int t4 = 0; t4 < 4; t4++) {
            int p = (wv * 4 + t4) * 64 + lane;
            int row = p >> 3, cp = p & 7;
            int gc = cp ^ (row & 7);
            const ushort_t* g = Kb + ((size_t)bh * 2048 + kt + row) * 64 + gc * 8;
            __builtin_amdgcn_global_load_lds((const AS_GLB unsigned int*)g,
                                             (AS_LDS unsigned int*)&Ks[(size_t)(wv * 4 + t4) * 64 * 8],
                                             16, 0, 0);
        }
        // ---- stage Vt rows 0..63: 64 rows x 16 chunks, pos = row*16 + (c ^ (row&15)) ----
#pragma unroll
        for (int t4 = 0; t4 < 4; t4++) {
            int p = (wv * 4 + t4) * 64 + lane;
            int row = p >> 4, cp = p & 15;
            int gc = cp ^ (row & 15);
            const ushort_t* g = VtG + ((size_t)bh * 65 + row) * 2048 + kt + gc * 8;
            __builtin_amdgcn_global_load_lds((const AS_GLB unsigned int*)g,
                                             (AS_LDS unsigned int*)&Vs[(size_t)(wv * 4 + t4) * 64 * 8],
                                             16, 0, 0);
        }
        // mask row 64 -> chunks 1024..1039 (row&15==0: no swizzle)
        if (tid < 64) {
            unsigned int mv = *reinterpret_cast<const unsigned int*>(
                VtG + ((size_t)bh * 65 + 64) * 2048 + kt + tid * 2);
            reinterpret_cast<unsigned int*>(&Vs[1024 * 8])[tid] = mv;
        }
        __syncthreads();

        // ---- QK^T: scores for this wave's 16 q rows x 128 keys ----
        floatx4 sacc[8];
#pragma unroll
        for (int j = 0; j < 8; j++) sacc[j] = (floatx4){0.f, 0.f, 0.f, 0.f};
#pragma unroll
        for (int j = 0; j < 8; j++) {
            int row = j * 16 + lm;
#pragma unroll
            for (int kc = 0; kc < 2; kc++) {
                int c = kc * 4 + quad;
                int pos = row * 8 + (c ^ (row & 7));
                bf16x8 bk = *reinterpret_cast<const bf16x8*>(&Ks[pos * 8]);
                sacc[j] = __builtin_amdgcn_mfma_f32_16x16x32_bf16(qf[kc], bk, sacc[j], 0, 0, 0);
            }
        }

        // ---- taylor weights -> P (bf16, swizzled) ----
#pragma unroll
        for (int j = 0; j < 8; j++)
#pragma unroll
            for (int r = 0; r < 4; r++) {
                float s = sacc[j][r];
                float wgt = fmaf(s, fmaf(s, 0.0078125f, 0.125f), 1.0f);  // 1 + s/8 + s^2/128
                int m = wv * 16 + quad * 4 + r;
                int col = j * 16 + lm;
                int cw = col >> 3;
                int pos = m * 16 + (cw ^ (m & 15));
                Ps[pos * 8 + (col & 7)] = f2bfu(wgt);
            }
        __syncthreads();

        // ---- P @ V': O[16 q][80] (col 64 = denominator) ----
#pragma unroll
        for (int j = 0; j < 5; j++) {
            int vrow = j * 16 + lm;
#pragma unroll
            for (int kc = 0; kc < 4; kc++) {
                int c = kc * 4 + quad;
                int ppos = (wv * 16 + lm) * 16 + (c ^ lm);
                bf16x8 pa = *reinterpret_cast<const bf16x8*>(&Ps[ppos * 8]);
                int vpos = vrow * 16 + (c ^ (vrow & 15));
                bf16x8 vb = *reinterpret_cast<const bf16x8*>(&Vs[vpos * 8]);
                oacc[j] = __builtin_amdgcn_mfma_f32_16x16x32_bf16(pa, vb, oacc[j], 0, 0, 0);
            }
        }
        __syncthreads();
    }

    // ---- epilogue: normalize, hi/lo split, write A2 [h|l|h] ----
    float den[4];
#pragma unroll
    for (int r = 0; r < 4; r++) den[r] = __shfl(oacc[4][r], quad * 16, 64);
#pragma unroll
    for (int j = 0; j < 4; j++) {
        int col = h * 64 + j * 16 + lm;
#pragma unroll
        for (int r = 0; r < 4; r++) {
            float v = oacc[j][r] / den[r];
            unsigned short hu = f2bfu(v);
            float hf = bf2f(hu);
            unsigned short lu = f2bfu(v - hf);
            size_t base = (size_t)(b * 2048 + qt * 64 + wv * 16 + quad * 4 + r) * 1536 + col;
            attnA2[base] = hu;
            attnA2[base + 512] = lu;
            attnA2[base + 1024] = hu;
        }
    }
}

extern "C" void kernel_launch(void* const* d_in, const int* in_sizes, int n_in,
                              void* d_out, int out_size, void* d_ws, size_t ws_size,
                              hipStream_t stream) {
    (void)in_sizes; (void)n_in; (void)out_size; (void)ws_size;
    const float* x    = (const float*)d_in[0];
    const void*  mask = d_in[1];
    const float* rot  = (const float*)d_in[2];
    const float* Wt   = (const float*)d_in[3];
    const float* Wo   = (const float*)d_in[4];

    char* ws = (char*)d_ws;
    int* flags      = (int*)ws;                                  // 64 B
    int* wmask      = (int*)(ws + 64);                           // 16 KB
    float* t        = (float*)(ws + 32768);                      // 25,165,824 B
    ushort_t* A2    = (ushort_t*)(ws + 32768 + 25165824);        // 12,582,912 B  (x-split, then attn-split)
    ushort_t* B2t   = (ushort_t*)(ws + 32768 + 25165824 + 12582912); // 4,718,592 B (Wt split / Qb / Wo split)
    ushort_t* Qb    = B2t;                                       // alias: live only between gemm1 and gemm2-prep
    ushort_t* Kb    = (ushort_t*)((char*)B2t + 4718592);         // 4,194,304 B
    ushort_t* VtG   = (ushort_t*)((char*)Kb + 4194304);          // 4,259,840 B  total ~48.6 MB

    tmha_detect<<<1, 256, 0, stream>>>((const unsigned char*)x, (const unsigned char*)mask, flags);
    tmha_decode_mask<<<16, 256, 0, stream>>>((const unsigned char*)mask, flags, wmask);

    // ---- gemm1: t = x @ W_trans^T via split-bf16 MFMA ----
    prep_split_a<<<(ROWS_ * DIM_) / 256, 256, 0, stream>>>(x, A2, ROWS_ * DIM_);
    prep_split_b<<<(TOUT_ * DIM_) / 256, 256, 0, stream>>>(Wt, B2t, TOUT_ * DIM_);
    {
        dim3 grid(TOUT_ / 128, ROWS_ / 128);
        mfma_gemm_bt<ROWS_, TOUT_, 1536><<<grid, 256, 0, stream>>>(A2, B2t, t);
    }

    tmha_rot<<<ROWS_, 256, 0, stream>>>(rot, wmask, t);

    // ---- attention preps (t -> bf16 head-major Q/K, masked V^T + mask row) ----
    prep_qk<<<ROWS_, 256, 0, stream>>>(t, Qb, Kb);
    {
        dim3 grid(32, 16);
        prep_vt<<<grid, 256, 0, stream>>>(t, wmask, VtG);
    }

    // ---- MFMA flash taylor-attention -> A2 (split layout) ----
    {
        dim3 grid(32, 8, 2);
        tmha_attn_mfma<<<grid, 256, 0, stream>>>(Qb, Kb, VtG, A2);
    }

    // ---- gemm2: out = attn @ W_o^T via split-bf16 MFMA ----
    prep_split_b<<<(DIM_ * DIM_) / 256, 256, 0, stream>>>(Wo, B2t, DIM_ * DIM_);
    {
        dim3 grid(DIM_ / 128, ROWS_ / 128);
        mfma_gemm_bt<ROWS_, DIM_, 1536><<<grid, 256, 0, stream>>>(A2, B2t, (float*)d_out);
    }
}

// Round 5
// 207.730 us; speedup vs baseline: 12.4985x; 1.2370x over previous
//
#include <hip/hip_runtime.h>
#include <hip/hip_bf16.h>

// Problem constants
#define B_    2
#define S_    2048
#define DIM_  512
#define H_    8
#define HD_   64
#define TOUT_ 1536   // 2*QK + DIM
#define ROWS_ (B_ * S_)   // 4096

typedef unsigned short ushort_t;
typedef __attribute__((ext_vector_type(8))) __bf16 bf16x8;
typedef __attribute__((ext_vector_type(4))) float floatx4;

#define AS_GLB __attribute__((address_space(1)))
#define AS_LDS __attribute__((address_space(3)))

// ---------- numeric helpers ----------
__device__ __forceinline__ float bf2f(unsigned int u) { return __uint_as_float(u << 16); }
__device__ __forceinline__ unsigned short f2bfu(float f) {
    unsigned u = __float_as_uint(f);
    unsigned r = (u + 0x7fffu + ((u >> 16) & 1u)) >> 16;
    return (unsigned short)r;
}

// ---------- mask classification (proven R1-R4) ----------
__global__ void tmha_detect(const unsigned char* mb, int* flags) {
    __shared__ int s_bf, s_f, s_u8;
    int tid = threadIdx.x;
    if (tid == 0) { s_bf = 0; s_f = 0; s_u8 = 0; }
    __syncthreads();
    int cbf = 0, cf = 0, cu8 = 0;
    for (int i = tid; i < 4096; i += 256) {
        unsigned char v = mb[i];
        if (v == 0x3F || v == 0x80) {
            cf++;
            if ((i & 3) == 1) cbf++;
        } else if (v != 0 && (i & 3) != 0) {
            cu8++;
        }
    }
    atomicAdd(&s_bf, cbf); atomicAdd(&s_f, cf); atomicAdd(&s_u8, cu8);
    __syncthreads();
    if (tid == 0) {
        int mcls;
        if (s_bf > 0)      mcls = 2;
        else if (s_f > 0)  mcls = 3;
        else if (s_u8 > 0) mcls = 0;
        else               mcls = 1;
        flags[1] = mcls;
    }
}

__global__ void tmha_decode_mask(const unsigned char* mb, const int* flags, int* wm) {
    int i = blockIdx.x * 256 + threadIdx.x;
    if (i >= ROWS_) return;
    int cls = flags[1];
    int v;
    if (cls == 0)      v = (mb[i] != 0);
    else if (cls == 1) v = (reinterpret_cast<const int*>(mb)[i] != 0);
    else if (cls == 2) v = ((reinterpret_cast<const unsigned short*>(mb)[i] & 0x7fffu) != 0);
    else               v = ((reinterpret_cast<const unsigned int*>(mb)[i] & 0x7fffffffu) != 0);
    wm[i] = v;
}

// ---------- fp32 -> bf16 cast (vectorized) ----------
__global__ __launch_bounds__(256) void cast_bf16(const float* __restrict__ src,
                                                 ushort_t* __restrict__ dst, int n4) {
    int i = blockIdx.x * 256 + threadIdx.x;
    if (i >= n4) return;
    float4 v = reinterpret_cast<const float4*>(src)[i];
    ushort_t o[4] = {f2bfu(v.x), f2bfu(v.y), f2bfu(v.z), f2bfu(v.w)};
    reinterpret_cast<uint2*>(dst)[i] = *reinterpret_cast<uint2*>(o);
}

// ==================================================================
// MFMA GEMM: C[M,N-tilewise] = A[M,K] @ B[N,K]^T  (bf16 in, fp32 out)
// Tile TM x 128, BK=64. 256 thr = 4 waves (2x2); wave = (TM/2) x 64.
// XOR-swizzled LDS: chunk c (16 B) of row r at pos r*8 + (c ^ (r&7))
// -> fragment b128 reads are 2-way max (free).  grid = (N/128, M/TM).
// ==================================================================
template <int TM, int N, int K>
__global__ __launch_bounds__(256) void mfma_gemm_bt(const ushort_t* __restrict__ A,
                                                    const ushort_t* __restrict__ Bm,
                                                    float* __restrict__ C) {
    constexpr int FM = TM / 32;                 // A fragments per wave
    __shared__ __align__(16) ushort_t As[TM * 64];
    __shared__ __align__(16) ushort_t Bs[128 * 64];
    int tid = threadIdx.x;
    int lane = tid & 63;
    int wv = tid >> 6;
    int wm = wv >> 1, wn = wv & 1;
    int quad = lane >> 4;
    int mrow = lane & 15;
    int bx = blockIdx.x;
    int by = blockIdx.y;

    floatx4 acc[FM][4];
#pragma unroll
    for (int i = 0; i < FM; i++)
#pragma unroll
        for (int j = 0; j < 4; j++) acc[i][j] = (floatx4){0.f, 0.f, 0.f, 0.f};

    for (int k0 = 0; k0 < K; k0 += 64) {
        // stage A: TM rows x 8 chunks, swizzled
#pragma unroll
        for (int t = 0; t < TM / 32; t++) {
            int p = (wv * (TM / 32) + t) * 64 + lane;
            int row = p >> 3, cp = p & 7;
            int gc = cp ^ (row & 7);
            const ushort_t* ga = A + (size_t)(by * TM + row) * K + k0 + gc * 8;
            __builtin_amdgcn_global_load_lds((const AS_GLB unsigned int*)ga,
                                             (AS_LDS unsigned int*)&As[(size_t)(wv * (TM / 32) + t) * 64 * 8],
                                             16, 0, 0);
        }
        // stage B: 128 rows x 8 chunks, swizzled
#pragma unroll
        for (int t = 0; t < 4; t++) {
            int p = (wv * 4 + t) * 64 + lane;
            int row = p >> 3, cp = p & 7;
            int gc = cp ^ (row & 7);
            const ushort_t* gb = Bm + (size_t)(bx * 128 + row) * K + k0 + gc * 8;
            __builtin_amdgcn_global_load_lds((const AS_GLB unsigned int*)gb,
                                             (AS_LDS unsigned int*)&Bs[(size_t)(wv * 4 + t) * 64 * 8],
                                             16, 0, 0);
        }
        __syncthreads();
#pragma unroll
        for (int ks = 0; ks < 64; ks += 32) {
            int c = (ks >> 3) + quad;
            bf16x8 af[FM], bf[4];
#pragma unroll
            for (int i = 0; i < FM; i++) {
                int row = wm * (TM / 2) + i * 16 + mrow;
                int pos = row * 8 + (c ^ (row & 7));
                af[i] = *reinterpret_cast<const bf16x8*>(&As[pos * 8]);
            }
#pragma unroll
            for (int j = 0; j < 4; j++) {
                int row = wn * 64 + j * 16 + mrow;
                int pos = row * 8 + (c ^ (row & 7));
                bf[j] = *reinterpret_cast<const bf16x8*>(&Bs[pos * 8]);
            }
#pragma unroll
            for (int i = 0; i < FM; i++)
#pragma unroll
                for (int j = 0; j < 4; j++)
                    acc[i][j] = __builtin_amdgcn_mfma_f32_16x16x32_bf16(af[i], bf[j], acc[i][j], 0, 0, 0);
        }
        __syncthreads();
    }

    // C/D layout: col = lane&15, row = quad*4 + reg
    int col0 = bx * 128 + wn * 64 + mrow;
    int row0 = by * TM + wm * (TM / 2) + quad * 4;
#pragma unroll
    for (int i = 0; i < FM; i++)
#pragma unroll
        for (int j = 0; j < 4; j++)
#pragma unroll
            for (int r = 0; r < 4; r++)
                C[(size_t)(row0 + i * 16 + r) * N + col0 + j * 16] = acc[i][j][r];
}

// ---------- fused rotate + q/k bf16 pack: t(q,k) -> Qb/Kb [bh][s][64] ----------
__global__ __launch_bounds__(256) void rot_qk(const float* __restrict__ t,
                                              const float* __restrict__ rotG,
                                              const int* __restrict__ wm,
                                              ushort_t* __restrict__ Qb,
                                              ushort_t* __restrict__ Kb) {
    __shared__ float rotT[64 * 65];       // rotT[j*65+i] = rot[i][j]
    __shared__ float qk[1024];
    int row = blockIdx.x;                 // b*2048 + s
    int tid = threadIdx.x;
    int b = row >> 11, s = row & 2047;

    float4 mine = *reinterpret_cast<const float4*>(t + (size_t)row * TOUT_ + tid * 4);
    float out[4];

    if (wm[row]) {
        *reinterpret_cast<float4*>(&qk[tid * 4]) = mine;
        const float* rp = rotG + (size_t)row * 4096;
        for (int e = tid * 4; e < 4096; e += 1024) {
            float4 v = *reinterpret_cast<const float4*>(rp + e);
            int i = e >> 6, j = e & 63;
            rotT[(j + 0) * 65 + i] = v.x;
            rotT[(j + 1) * 65 + i] = v.y;
            rotT[(j + 2) * 65 + i] = v.z;
            rotT[(j + 3) * 65 + i] = v.w;
        }
        __syncthreads();
#pragma unroll
        for (int r = 0; r < 4; r++) {
            int u = tid * 4 + r;
            int i = u & 63;
            int base = u & ~63;           // sel*512 + h*64
            float acc = 0.f;
            for (int j = 0; j < 64; j++) acc += rotT[j * 65 + i] * qk[base + j];
            out[r] = acc;
        }
    } else {
        out[0] = mine.x; out[1] = mine.y; out[2] = mine.z; out[3] = mine.w;
    }

    int u0 = tid * 4;
    int sel = u0 >> 9;                    // 0 = q, 1 = k
    int c = u0 & 511;
    int h = c >> 6, d = c & 63;
    ushort_t* dst = (sel ? Kb : Qb) + ((size_t)(b * 8 + h) * 2048 + s) * 64 + d;
    ushort_t o[4] = {f2bfu(out[0]), f2bfu(out[1]), f2bfu(out[2]), f2bfu(out[3])};
    *reinterpret_cast<uint2*>(dst) = *reinterpret_cast<uint2*>(o);
}

// ---------- prep: V^T bf16 [bh][65][2048]; masked keys zeroed; row 64 = mask (proven R4) ----------
__global__ __launch_bounds__(256) void prep_vt(const float* __restrict__ t,
                                               const int* __restrict__ wm,
                                               ushort_t* __restrict__ VtG) {
    __shared__ float tile[64][65];
    __shared__ float mrow[64];
    int st = blockIdx.x;   // 0..31 (64-key tile)
    int bh = blockIdx.y;   // 0..15
    int b = bh >> 3, h = bh & 7;
    int tid = threadIdx.x;
    if (tid < 64) mrow[tid] = wm[b * 2048 + st * 64 + tid] ? 1.0f : 0.0f;
#pragma unroll
    for (int i = 0; i < 4; i++) {
        int q = i * 256 + tid;
        int r = q >> 4, c4 = (q & 15) * 4;
        float4 v = *reinterpret_cast<const float4*>(
            t + (size_t)(b * 2048 + st * 64 + r) * TOUT_ + 1024 + h * 64 + c4);
        tile[r][c4] = v.x; tile[r][c4 + 1] = v.y; tile[r][c4 + 2] = v.z; tile[r][c4 + 3] = v.w;
    }
    __syncthreads();
#pragma unroll
    for (int i = 0; i < 8; i++) {
        int e = i * 256 + tid;
        int d = e >> 5, sl = (e & 31) * 2;
        float v0 = tile[sl][d] * mrow[sl];
        float v1 = tile[sl + 1][d] * mrow[sl + 1];
        unsigned int u = (unsigned)f2bfu(v0) | ((unsigned)f2bfu(v1) << 16);
        *reinterpret_cast<unsigned int*>(VtG + ((size_t)bh * 65 + d) * 2048 + st * 64 + sl) = u;
    }
    if (tid < 32) {
        int sl = tid * 2;
        unsigned m0 = mrow[sl]     != 0.f ? 0x3F80u : 0u;
        unsigned m1 = mrow[sl + 1] != 0.f ? 0x3F80u : 0u;
        *reinterpret_cast<unsigned int*>(VtG + ((size_t)bh * 65 + 64) * 2048 + st * 64 + sl) = m0 | (m1 << 16);
    }
}

// ==================================================================
// MFMA flash taylor-attention (proven R4). Epilogue now writes plain
// bf16 attn [4096][512] for the plain-bf16 gemm2.
// ==================================================================
__global__ __launch_bounds__(256) void tmha_attn_mfma(const ushort_t* __restrict__ Qb,
                                                      const ushort_t* __restrict__ Kb,
                                                      const ushort_t* __restrict__ VtG,
                                                      ushort_t* __restrict__ attnAb) {
    __shared__ __align__(16) ushort_t Ks[1024 * 8];   // 128 keys x 8 chunks (16 KB)
    __shared__ __align__(16) ushort_t Vs[1280 * 8];   // 80 dims x 16 chunks (20 KB)
    __shared__ __align__(16) ushort_t Ps[1024 * 8];   // 64 q x 16 chunks (16 KB)
    int tid = threadIdx.x;
    int lane = tid & 63;
    int wv = tid >> 6;
    int lm = lane & 15;
    int quad = lane >> 4;
    int qt = blockIdx.x;
    int h = blockIdx.y;
    int b = blockIdx.z;
    int bh = b * 8 + h;

    // zero Vs rows 65..79 once
    for (int i = tid; i < 960; i += 256)
        reinterpret_cast<unsigned int*>(&Vs[1040 * 8])[i] = 0u;

    bf16x8 qf[2];
    {
        const ushort_t* qp = Qb + ((size_t)bh * 2048 + qt * 64 + wv * 16 + lm) * 64 + quad * 8;
        qf[0] = *reinterpret_cast<const bf16x8*>(qp);
        qf[1] = *reinterpret_cast<const bf16x8*>(qp + 32);
    }

    floatx4 oacc[5];
#pragma unroll
    for (int j = 0; j < 5; j++) oacc[j] = (floatx4){0.f, 0.f, 0.f, 0.f};

    for (int kt = 0; kt < S_; kt += 128) {
#pragma unroll
        for (int t4 = 0; t4 < 4; t4++) {
            int p = (wv * 4 + t4) * 64 + lane;
            int row = p >> 3, cp = p & 7;
            int gc = cp ^ (row & 7);
            const ushort_t* g = Kb + ((size_t)bh * 2048 + kt + row) * 64 + gc * 8;
            __builtin_amdgcn_global_load_lds((const AS_GLB unsigned int*)g,
                                             (AS_LDS unsigned int*)&Ks[(size_t)(wv * 4 + t4) * 64 * 8],
                                             16, 0, 0);
        }
#pragma unroll
        for (int t4 = 0; t4 < 4; t4++) {
            int p = (wv * 4 + t4) * 64 + lane;
            int row = p >> 4, cp = p & 15;
            int gc = cp ^ (row & 15);
            const ushort_t* g = VtG + ((size_t)bh * 65 + row) * 2048 + kt + gc * 8;
            __builtin_amdgcn_global_load_lds((const AS_GLB unsigned int*)g,
                                             (AS_LDS unsigned int*)&Vs[(size_t)(wv * 4 + t4) * 64 * 8],
                                             16, 0, 0);
        }
        if (tid < 64) {
            unsigned int mv = *reinterpret_cast<const unsigned int*>(
                VtG + ((size_t)bh * 65 + 64) * 2048 + kt + tid * 2);
            reinterpret_cast<unsigned int*>(&Vs[1024 * 8])[tid] = mv;
        }
        __syncthreads();

        floatx4 sacc[8];
#pragma unroll
        for (int j = 0; j < 8; j++) sacc[j] = (floatx4){0.f, 0.f, 0.f, 0.f};
#pragma unroll
        for (int j = 0; j < 8; j++) {
            int row = j * 16 + lm;
#pragma unroll
            for (int kc = 0; kc < 2; kc++) {
                int c = kc * 4 + quad;
                int pos = row * 8 + (c ^ (row & 7));
                bf16x8 bk = *reinterpret_cast<const bf16x8*>(&Ks[pos * 8]);
                sacc[j] = __builtin_amdgcn_mfma_f32_16x16x32_bf16(qf[kc], bk, sacc[j], 0, 0, 0);
            }
        }

#pragma unroll
        for (int j = 0; j < 8; j++)
#pragma unroll
            for (int r = 0; r < 4; r++) {
                float s = sacc[j][r];
                float wgt = fmaf(s, fmaf(s, 0.0078125f, 0.125f), 1.0f);  // 1 + s/8 + s^2/128
                int m = wv * 16 + quad * 4 + r;
                int col = j * 16 + lm;
                int cw = col >> 3;
                int pos = m * 16 + (cw ^ (m & 15));
                Ps[pos * 8 + (col & 7)] = f2bfu(wgt);
            }
        __syncthreads();

#pragma unroll
        for (int j = 0; j < 5; j++) {
            int vrow = j * 16 + lm;
#pragma unroll
            for (int kc = 0; kc < 4; kc++) {
                int c = kc * 4 + quad;
                int ppos = (wv * 16 + lm) * 16 + (c ^ lm);
                bf16x8 pa = *reinterpret_cast<const bf16x8*>(&Ps[ppos * 8]);
                int vpos = vrow * 16 + (c ^ (vrow & 15));
                bf16x8 vb = *reinterpret_cast<const bf16x8*>(&Vs[vpos * 8]);
                oacc[j] = __builtin_amdgcn_mfma_f32_16x16x32_bf16(pa, vb, oacc[j], 0, 0, 0);
            }
        }
        __syncthreads();
    }

    float den[4];
#pragma unroll
    for (int r = 0; r < 4; r++) den[r] = __shfl(oacc[4][r], quad * 16, 64);
#pragma unroll
    for (int j = 0; j < 4; j++) {
        int col = h * 64 + j * 16 + lm;
#pragma unroll
        for (int r = 0; r < 4; r++) {
            float v = oacc[j][r] / den[r];
            attnAb[(size_t)(b * 2048 + qt * 64 + wv * 16 + quad * 4 + r) * DIM_ + col] = f2bfu(v);
        }
    }
}

extern "C" void kernel_launch(void* const* d_in, const int* in_sizes, int n_in,
                              void* d_out, int out_size, void* d_ws, size_t ws_size,
                              hipStream_t stream) {
    (void)in_sizes; (void)n_in; (void)out_size; (void)ws_size;
    const float* x    = (const float*)d_in[0];
    const void*  mask = d_in[1];
    const float* rot  = (const float*)d_in[2];
    const float* Wt   = (const float*)d_in[3];
    const float* Wo   = (const float*)d_in[4];

    char* ws = (char*)d_ws;
    int* flags       = (int*)ws;                            // 64 B
    int* wmask       = (int*)(ws + 64);                     // 16 KB
    float* t         = (float*)(ws + 32768);                // 25,165,824 B
    ushort_t* Xb     = (ushort_t*)(ws + 25198592);          //  4,194,304 B
    ushort_t* Wtb    = (ushort_t*)(ws + 29392896);          //  1,572,864 B
    ushort_t* Wob    = (ushort_t*)(ws + 30965760);          //    524,288 B
    ushort_t* Qb     = (ushort_t*)(ws + 31490048);          //  4,194,304 B
    ushort_t* Kb     = (ushort_t*)(ws + 35684352);          //  4,194,304 B
    ushort_t* VtG    = (ushort_t*)(ws + 39878656);          //  4,259,840 B
    ushort_t* attnAb = (ushort_t*)(ws + 44138496);          //  4,194,304 B -> ends 48,332,800

    tmha_detect<<<1, 256, 0, stream>>>((const unsigned char*)mask, flags);
    tmha_decode_mask<<<16, 256, 0, stream>>>((const unsigned char*)mask, flags, wmask);

    // bf16 casts
    cast_bf16<<<(ROWS_ * DIM_ / 4 + 255) / 256, 256, 0, stream>>>(x, Xb, ROWS_ * DIM_ / 4);
    cast_bf16<<<(TOUT_ * DIM_ / 4 + 255) / 256, 256, 0, stream>>>(Wt, Wtb, TOUT_ * DIM_ / 4);
    cast_bf16<<<(DIM_ * DIM_ / 4 + 255) / 256, 256, 0, stream>>>(Wo, Wob, DIM_ * DIM_ / 4);

    // gemm1: t = x @ Wt^T  (plain bf16, TM=64 -> 768 blocks = 3/CU)
    {
        dim3 grid(TOUT_ / 128, ROWS_ / 64);
        mfma_gemm_bt<64, TOUT_, DIM_><<<grid, 256, 0, stream>>>(Xb, Wtb, t);
    }

    // fused rotation + q/k bf16 pack
    rot_qk<<<ROWS_, 256, 0, stream>>>(t, rot, wmask, Qb, Kb);

    // masked V^T + mask-row prep
    {
        dim3 grid(32, 16);
        prep_vt<<<grid, 256, 0, stream>>>(t, wmask, VtG);
    }

    // MFMA flash taylor-attention
    {
        dim3 grid(32, 8, 2);
        tmha_attn_mfma<<<grid, 256, 0, stream>>>(Qb, Kb, VtG, attnAb);
    }

    // gemm2: out = attn @ Wo^T  (plain bf16, TM=64 -> 256 blocks = 1/CU)
    {
        dim3 grid(DIM_ / 128, ROWS_ / 64);
        mfma_gemm_bt<64, DIM_, DIM_><<<grid, 256, 0, stream>>>(attnAb, Wob, (float*)d_out);
    }
}

// Round 6
// 204.243 us; speedup vs baseline: 12.7119x; 1.0171x over previous
//
#include <hip/hip_runtime.h>
#include <hip/hip_bf16.h>

// Problem constants
#define B_    2
#define S_    2048
#define DIM_  512
#define H_    8
#define HD_   64
#define TOUT_ 1536   // 2*QK + DIM
#define ROWS_ (B_ * S_)   // 4096

typedef unsigned short ushort_t;
typedef __attribute__((ext_vector_type(8))) __bf16 bf16x8;
typedef __attribute__((ext_vector_type(4))) float floatx4;

#define AS_GLB __attribute__((address_space(1)))
#define AS_LDS __attribute__((address_space(3)))

// ---------- numeric helpers ----------
__device__ __forceinline__ float bf2f(unsigned int u) { return __uint_as_float(u << 16); }
__device__ __forceinline__ unsigned short f2bfu(float f) {
    unsigned u = __float_as_uint(f);
    unsigned r = (u + 0x7fffu + ((u >> 16) & 1u)) >> 16;
    return (unsigned short)r;
}
__device__ __forceinline__ bf16x8 cvt8(const float* p) {
    float4 a = *reinterpret_cast<const float4*>(p);
    float4 b = *reinterpret_cast<const float4*>(p + 4);
    ushort_t o[8] = {f2bfu(a.x), f2bfu(a.y), f2bfu(a.z), f2bfu(a.w),
                     f2bfu(b.x), f2bfu(b.y), f2bfu(b.z), f2bfu(b.w)};
    return *reinterpret_cast<bf16x8*>(o);
}

// ---------- mask classification (proven R1-R5) ----------
__global__ void tmha_detect(const unsigned char* mb, int* flags) {
    __shared__ int s_bf, s_f, s_u8;
    int tid = threadIdx.x;
    if (tid == 0) { s_bf = 0; s_f = 0; s_u8 = 0; }
    __syncthreads();
    int cbf = 0, cf = 0, cu8 = 0;
    for (int i = tid; i < 4096; i += 256) {
        unsigned char v = mb[i];
        if (v == 0x3F || v == 0x80) {
            cf++;
            if ((i & 3) == 1) cbf++;
        } else if (v != 0 && (i & 3) != 0) {
            cu8++;
        }
    }
    atomicAdd(&s_bf, cbf); atomicAdd(&s_f, cf); atomicAdd(&s_u8, cu8);
    __syncthreads();
    if (tid == 0) {
        int mcls;
        if (s_bf > 0)      mcls = 2;
        else if (s_f > 0)  mcls = 3;
        else if (s_u8 > 0) mcls = 0;
        else               mcls = 1;
        flags[1] = mcls;
    }
}

__global__ void tmha_decode_mask(const unsigned char* mb, const int* flags, int* wm) {
    int i = blockIdx.x * 256 + threadIdx.x;
    if (i >= ROWS_) return;
    int cls = flags[1];
    int v;
    if (cls == 0)      v = (mb[i] != 0);
    else if (cls == 1) v = (reinterpret_cast<const int*>(mb)[i] != 0);
    else if (cls == 2) v = ((reinterpret_cast<const unsigned short*>(mb)[i] & 0x7fffu) != 0);
    else               v = ((reinterpret_cast<const unsigned int*>(mb)[i] & 0x7fffffffu) != 0);
    wm[i] = v;
}

// ---------- fp32 -> bf16 cast (vectorized) ----------
__global__ __launch_bounds__(256) void cast_bf16(const float* __restrict__ src,
                                                 ushort_t* __restrict__ dst, int n4) {
    int i = blockIdx.x * 256 + threadIdx.x;
    if (i >= n4) return;
    float4 v = reinterpret_cast<const float4*>(src)[i];
    ushort_t o[4] = {f2bfu(v.x), f2bfu(v.y), f2bfu(v.z), f2bfu(v.w)};
    reinterpret_cast<uint2*>(dst)[i] = *reinterpret_cast<uint2*>(o);
}

// ==================================================================
// MFMA GEMM (proven R5): C[M,N] = A[M,K] @ B[N,K]^T, XOR-swizzled LDS.
// ==================================================================
template <int TM, int N, int K>
__global__ __launch_bounds__(256) void mfma_gemm_bt(const ushort_t* __restrict__ A,
                                                    const ushort_t* __restrict__ Bm,
                                                    float* __restrict__ C) {
    constexpr int FM = TM / 32;
    __shared__ __align__(16) ushort_t As[TM * 64];
    __shared__ __align__(16) ushort_t Bs[128 * 64];
    int tid = threadIdx.x;
    int lane = tid & 63;
    int wv = tid >> 6;
    int wm = wv >> 1, wn = wv & 1;
    int quad = lane >> 4;
    int mrow = lane & 15;
    int bx = blockIdx.x;
    int by = blockIdx.y;

    floatx4 acc[FM][4];
#pragma unroll
    for (int i = 0; i < FM; i++)
#pragma unroll
        for (int j = 0; j < 4; j++) acc[i][j] = (floatx4){0.f, 0.f, 0.f, 0.f};

    for (int k0 = 0; k0 < K; k0 += 64) {
#pragma unroll
        for (int t = 0; t < TM / 32; t++) {
            int p = (wv * (TM / 32) + t) * 64 + lane;
            int row = p >> 3, cp = p & 7;
            int gc = cp ^ (row & 7);
            const ushort_t* ga = A + (size_t)(by * TM + row) * K + k0 + gc * 8;
            __builtin_amdgcn_global_load_lds((const AS_GLB unsigned int*)ga,
                                             (AS_LDS unsigned int*)&As[(size_t)(wv * (TM / 32) + t) * 64 * 8],
                                             16, 0, 0);
        }
#pragma unroll
        for (int t = 0; t < 4; t++) {
            int p = (wv * 4 + t) * 64 + lane;
            int row = p >> 3, cp = p & 7;
            int gc = cp ^ (row & 7);
            const ushort_t* gb = Bm + (size_t)(bx * 128 + row) * K + k0 + gc * 8;
            __builtin_amdgcn_global_load_lds((const AS_GLB unsigned int*)gb,
                                             (AS_LDS unsigned int*)&Bs[(size_t)(wv * 4 + t) * 64 * 8],
                                             16, 0, 0);
        }
        __syncthreads();
#pragma unroll
        for (int ks = 0; ks < 64; ks += 32) {
            int c = (ks >> 3) + quad;
            bf16x8 af[FM], bf[4];
#pragma unroll
            for (int i = 0; i < FM; i++) {
                int row = wm * (TM / 2) + i * 16 + mrow;
                int pos = row * 8 + (c ^ (row & 7));
                af[i] = *reinterpret_cast<const bf16x8*>(&As[pos * 8]);
            }
#pragma unroll
            for (int j = 0; j < 4; j++) {
                int row = wn * 64 + j * 16 + mrow;
                int pos = row * 8 + (c ^ (row & 7));
                bf[j] = *reinterpret_cast<const bf16x8*>(&Bs[pos * 8]);
            }
#pragma unroll
            for (int i = 0; i < FM; i++)
#pragma unroll
                for (int j = 0; j < 4; j++)
                    acc[i][j] = __builtin_amdgcn_mfma_f32_16x16x32_bf16(af[i], bf[j], acc[i][j], 0, 0, 0);
        }
        __syncthreads();
    }

    int col0 = bx * 128 + wn * 64 + mrow;
    int row0 = by * TM + wm * (TM / 2) + quad * 4;
#pragma unroll
    for (int i = 0; i < FM; i++)
#pragma unroll
        for (int j = 0; j < 4; j++)
#pragma unroll
            for (int r = 0; r < 4; r++)
                C[(size_t)(row0 + i * 16 + r) * N + col0 + j * 16] = acc[i][j][r];
}

// ==================================================================
// MFMA rotation: per position s, out[16 vec][64] = in[16 vec][64] @ R_s^T
// (only if mask; else passthrough). One wave per s, no LDS, no barrier.
// A[m=vec][k=j]: lane(lm=vec) reads t row; B[n=i][k=j] = R[i][j] natural
// row-major. Writes Qb/Kb bf16 [bh][s][64] directly.
// ==================================================================
__global__ __launch_bounds__(256) void rot_qk_mfma(const float* __restrict__ t,
                                                   const float* __restrict__ rotG,
                                                   const int* __restrict__ wm,
                                                   ushort_t* __restrict__ Qb,
                                                   ushort_t* __restrict__ Kb) {
    int lane = threadIdx.x & 63;
    int wv = threadIdx.x >> 6;
    int row = blockIdx.x * 4 + wv;     // b*2048 + s
    int b = row >> 11, s = row & 2047;
    int lm = lane & 15, quad = lane >> 4;
    const float* trow = t + (size_t)row * TOUT_;

    if (wm[row]) {
        // A fragments: vec = lm, k = kc*32 + quad*8 + j
        bf16x8 af[2];
#pragma unroll
        for (int kc = 0; kc < 2; kc++)
            af[kc] = cvt8(trow + lm * 64 + kc * 32 + quad * 8);

        const float* R = rotG + (size_t)row * 4096;
        floatx4 dacc[4];
#pragma unroll
        for (int nb = 0; nb < 4; nb++) dacc[nb] = (floatx4){0.f, 0.f, 0.f, 0.f};
#pragma unroll
        for (int nb = 0; nb < 4; nb++)
#pragma unroll
            for (int kc = 0; kc < 2; kc++) {
                bf16x8 bfr = cvt8(R + (size_t)(nb * 16 + lm) * 64 + kc * 32 + quad * 8);
                dacc[nb] = __builtin_amdgcn_mfma_f32_16x16x32_bf16(af[kc], bfr, dacc[nb], 0, 0, 0);
            }
        // C/D: col(i) = lm, row(vec) = quad*4 + r
#pragma unroll
        for (int nb = 0; nb < 4; nb++)
#pragma unroll
            for (int r = 0; r < 4; r++) {
                int vec = quad * 4 + r;
                int h = vec & 7;
                ushort_t* dst = (vec >= 8 ? Kb : Qb);
                dst[((size_t)(b * 8 + h) * 2048 + s) * 64 + nb * 16 + lm] = f2bfu(dacc[nb][r]);
            }
    } else {
        // passthrough: out[vec][i] = in[vec][i]
#pragma unroll
        for (int nb = 0; nb < 4; nb++)
#pragma unroll
            for (int r = 0; r < 4; r++) {
                int vec = quad * 4 + r;
                int h = vec & 7;
                float v = trow[vec * 64 + nb * 16 + lm];
                ushort_t* dst = (vec >= 8 ? Kb : Qb);
                dst[((size_t)(b * 8 + h) * 2048 + s) * 64 + nb * 16 + lm] = f2bfu(v);
            }
    }
}

// ---------- prep: V^T bf16 [bh][65][2048]; masked keys zeroed; row 64 = mask (proven R4) ----------
__global__ __launch_bounds__(256) void prep_vt(const float* __restrict__ t,
                                               const int* __restrict__ wm,
                                               ushort_t* __restrict__ VtG) {
    __shared__ float tile[64][65];
    __shared__ float mrow[64];
    int st = blockIdx.x;   // 0..31 (64-key tile)
    int bh = blockIdx.y;   // 0..15
    int b = bh >> 3, h = bh & 7;
    int tid = threadIdx.x;
    if (tid < 64) mrow[tid] = wm[b * 2048 + st * 64 + tid] ? 1.0f : 0.0f;
#pragma unroll
    for (int i = 0; i < 4; i++) {
        int q = i * 256 + tid;
        int r = q >> 4, c4 = (q & 15) * 4;
        float4 v = *reinterpret_cast<const float4*>(
            t + (size_t)(b * 2048 + st * 64 + r) * TOUT_ + 1024 + h * 64 + c4);
        tile[r][c4] = v.x; tile[r][c4 + 1] = v.y; tile[r][c4 + 2] = v.z; tile[r][c4 + 3] = v.w;
    }
    __syncthreads();
#pragma unroll
    for (int i = 0; i < 8; i++) {
        int e = i * 256 + tid;
        int d = e >> 5, sl = (e & 31) * 2;
        float v0 = tile[sl][d] * mrow[sl];
        float v1 = tile[sl + 1][d] * mrow[sl + 1];
        unsigned int u = (unsigned)f2bfu(v0) | ((unsigned)f2bfu(v1) << 16);
        *reinterpret_cast<unsigned int*>(VtG + ((size_t)bh * 65 + d) * 2048 + st * 64 + sl) = u;
    }
    if (tid < 32) {
        int sl = tid * 2;
        unsigned m0 = mrow[sl]     != 0.f ? 0x3F80u : 0u;
        unsigned m1 = mrow[sl + 1] != 0.f ? 0x3F80u : 0u;
        *reinterpret_cast<unsigned int*>(VtG + ((size_t)bh * 65 + 64) * 2048 + st * 64 + sl) = m0 | (m1 << 16);
    }
}

// ==================================================================
// MFMA flash taylor-attention, v2: 128 thr = 2 waves, 32 q-rows/wave
// (2 A-fragments per B-read -> halved LDS traffic per MFMA).
// Block = 64 q-rows; grid (32, 8, 2) = 512 = 2 blocks/CU; LDS 52 KB.
// ==================================================================
__global__ __launch_bounds__(128) void tmha_attn_mfma(const ushort_t* __restrict__ Qb,
                                                      const ushort_t* __restrict__ Kb,
                                                      const ushort_t* __restrict__ VtG,
                                                      ushort_t* __restrict__ attnAb) {
    __shared__ __align__(16) ushort_t Ks[1024 * 8];   // 128 keys x 8 chunks (16 KB)
    __shared__ __align__(16) ushort_t Vs[1280 * 8];   // 80 dims x 16 chunks (20 KB)
    __shared__ __align__(16) ushort_t Ps[1024 * 8];   // 64 q x 16 chunks (16 KB)
    int tid = threadIdx.x;
    int lane = tid & 63;
    int wv = tid >> 6;                 // 0..1
    int lm = lane & 15;
    int quad = lane >> 4;
    int qt = blockIdx.x;
    int h = blockIdx.y;
    int b = blockIdx.z;
    int bh = b * 8 + h;

    // zero Vs rows 65..79 once
    for (int i = tid; i < 960; i += 128)
        reinterpret_cast<unsigned int*>(&Vs[1040 * 8])[i] = 0u;

    // Q fragments: wave owns 32 q rows as 2 m-blocks
    bf16x8 qf[2][2];
#pragma unroll
    for (int mi = 0; mi < 2; mi++) {
        const ushort_t* qp = Qb + ((size_t)bh * 2048 + qt * 64 + wv * 32 + mi * 16 + lm) * 64 + quad * 8;
        qf[mi][0] = *reinterpret_cast<const bf16x8*>(qp);
        qf[mi][1] = *reinterpret_cast<const bf16x8*>(qp + 32);
    }

    floatx4 oacc[2][5];
#pragma unroll
    for (int mi = 0; mi < 2; mi++)
#pragma unroll
        for (int j = 0; j < 5; j++) oacc[mi][j] = (floatx4){0.f, 0.f, 0.f, 0.f};

    for (int kt = 0; kt < S_; kt += 128) {
        // stage K: 128 rows x 8 chunks, swizzled
#pragma unroll
        for (int t4 = 0; t4 < 8; t4++) {
            int p = (wv * 8 + t4) * 64 + lane;
            int row = p >> 3, cp = p & 7;
            int gc = cp ^ (row & 7);
            const ushort_t* g = Kb + ((size_t)bh * 2048 + kt + row) * 64 + gc * 8;
            __builtin_amdgcn_global_load_lds((const AS_GLB unsigned int*)g,
                                             (AS_LDS unsigned int*)&Ks[(size_t)(wv * 8 + t4) * 64 * 8],
                                             16, 0, 0);
        }
        // stage Vt rows 0..63: 64 rows x 16 chunks, swizzled
#pragma unroll
        for (int t4 = 0; t4 < 8; t4++) {
            int p = (wv * 8 + t4) * 64 + lane;
            int row = p >> 4, cp = p & 15;
            int gc = cp ^ (row & 15);
            const ushort_t* g = VtG + ((size_t)bh * 65 + row) * 2048 + kt + gc * 8;
            __builtin_amdgcn_global_load_lds((const AS_GLB unsigned int*)g,
                                             (AS_LDS unsigned int*)&Vs[(size_t)(wv * 8 + t4) * 64 * 8],
                                             16, 0, 0);
        }
        // mask row 64 (no swizzle: 64&15==0)
        if (tid < 64) {
            unsigned int mv = *reinterpret_cast<const unsigned int*>(
                VtG + ((size_t)bh * 65 + 64) * 2048 + kt + tid * 2);
            reinterpret_cast<unsigned int*>(&Vs[1024 * 8])[tid] = mv;
        }
        __syncthreads();

        // ---- QK^T: 32 q rows x 128 keys per wave ----
        floatx4 sacc[2][8];
#pragma unroll
        for (int mi = 0; mi < 2; mi++)
#pragma unroll
            for (int j = 0; j < 8; j++) sacc[mi][j] = (floatx4){0.f, 0.f, 0.f, 0.f};
#pragma unroll
        for (int j = 0; j < 8; j++) {
            int row = j * 16 + lm;
#pragma unroll
            for (int kc = 0; kc < 2; kc++) {
                int c = kc * 4 + quad;
                int pos = row * 8 + (c ^ (row & 7));
                bf16x8 bk = *reinterpret_cast<const bf16x8*>(&Ks[pos * 8]);
                sacc[0][j] = __builtin_amdgcn_mfma_f32_16x16x32_bf16(qf[0][kc], bk, sacc[0][j], 0, 0, 0);
                sacc[1][j] = __builtin_amdgcn_mfma_f32_16x16x32_bf16(qf[1][kc], bk, sacc[1][j], 0, 0, 0);
            }
        }

        // ---- taylor weights -> P (bf16, swizzled) ----
#pragma unroll
        for (int mi = 0; mi < 2; mi++)
#pragma unroll
            for (int j = 0; j < 8; j++)
#pragma unroll
                for (int r = 0; r < 4; r++) {
                    float s = sacc[mi][j][r];
                    float wgt = fmaf(s, fmaf(s, 0.0078125f, 0.125f), 1.0f);  // 1 + s/8 + s^2/128
                    int m = wv * 32 + mi * 16 + quad * 4 + r;
                    int col = j * 16 + lm;
                    int cw = col >> 3;
                    int pos = m * 16 + (cw ^ (m & 15));
                    Ps[pos * 8 + (col & 7)] = f2bfu(wgt);
                }
        __syncthreads();

        // ---- P @ V': O[32 q][80] (col 64 = denominator) ----
#pragma unroll
        for (int kc = 0; kc < 4; kc++) {
            int c = kc * 4 + quad;
            bf16x8 pa[2];
#pragma unroll
            for (int mi = 0; mi < 2; mi++) {
                int row = wv * 32 + mi * 16 + lm;
                int pos = row * 16 + (c ^ (row & 15));
                pa[mi] = *reinterpret_cast<const bf16x8*>(&Ps[pos * 8]);
            }
#pragma unroll
            for (int j = 0; j < 5; j++) {
                int vrow = j * 16 + lm;
                int vpos = vrow * 16 + (c ^ (vrow & 15));
                bf16x8 vb = *reinterpret_cast<const bf16x8*>(&Vs[vpos * 8]);
                oacc[0][j] = __builtin_amdgcn_mfma_f32_16x16x32_bf16(pa[0], vb, oacc[0][j], 0, 0, 0);
                oacc[1][j] = __builtin_amdgcn_mfma_f32_16x16x32_bf16(pa[1], vb, oacc[1][j], 0, 0, 0);
            }
        }
        __syncthreads();
    }

    // ---- epilogue: normalize, write bf16 attn ----
#pragma unroll
    for (int mi = 0; mi < 2; mi++) {
        float den[4];
#pragma unroll
        for (int r = 0; r < 4; r++) den[r] = __shfl(oacc[mi][4][r], quad * 16, 64);
#pragma unroll
        for (int j = 0; j < 4; j++) {
            int col = h * 64 + j * 16 + lm;
#pragma unroll
            for (int r = 0; r < 4; r++) {
                float v = oacc[mi][j][r] / den[r];
                attnAb[(size_t)(b * 2048 + qt * 64 + wv * 32 + mi * 16 + quad * 4 + r) * DIM_ + col] = f2bfu(v);
            }
        }
    }
}

extern "C" void kernel_launch(void* const* d_in, const int* in_sizes, int n_in,
                              void* d_out, int out_size, void* d_ws, size_t ws_size,
                              hipStream_t stream) {
    (void)in_sizes; (void)n_in; (void)out_size; (void)ws_size;
    const float* x    = (const float*)d_in[0];
    const void*  mask = d_in[1];
    const float* rot  = (const float*)d_in[2];
    const float* Wt   = (const float*)d_in[3];
    const float* Wo   = (const float*)d_in[4];

    char* ws = (char*)d_ws;
    int* flags       = (int*)ws;                            // 64 B
    int* wmask       = (int*)(ws + 64);                     // 16 KB
    float* t         = (float*)(ws + 32768);                // 25,165,824 B
    ushort_t* Xb     = (ushort_t*)(ws + 25198592);          //  4,194,304 B
    ushort_t* Wtb    = (ushort_t*)(ws + 29392896);          //  1,572,864 B
    ushort_t* Wob    = (ushort_t*)(ws + 30965760);          //    524,288 B
    ushort_t* Qb     = (ushort_t*)(ws + 31490048);          //  4,194,304 B
    ushort_t* Kb     = (ushort_t*)(ws + 35684352);          //  4,194,304 B
    ushort_t* VtG    = (ushort_t*)(ws + 39878656);          //  4,259,840 B
    ushort_t* attnAb = (ushort_t*)(ws + 44138496);          //  4,194,304 B -> ends 48,332,800

    tmha_detect<<<1, 256, 0, stream>>>((const unsigned char*)mask, flags);
    tmha_decode_mask<<<16, 256, 0, stream>>>((const unsigned char*)mask, flags, wmask);

    // bf16 casts
    cast_bf16<<<(ROWS_ * DIM_ / 4 + 255) / 256, 256, 0, stream>>>(x, Xb, ROWS_ * DIM_ / 4);
    cast_bf16<<<(TOUT_ * DIM_ / 4 + 255) / 256, 256, 0, stream>>>(Wt, Wtb, TOUT_ * DIM_ / 4);
    cast_bf16<<<(DIM_ * DIM_ / 4 + 255) / 256, 256, 0, stream>>>(Wo, Wob, DIM_ * DIM_ / 4);

    // gemm1: t = x @ Wt^T  (TM=64 -> 768 blocks = 3/CU)
    {
        dim3 grid(TOUT_ / 128, ROWS_ / 64);
        mfma_gemm_bt<64, TOUT_, DIM_><<<grid, 256, 0, stream>>>(Xb, Wtb, t);
    }

    // MFMA rotation + q/k bf16 pack (1 wave per position, no LDS)
    rot_qk_mfma<<<ROWS_ / 4, 256, 0, stream>>>(t, rot, wmask, Qb, Kb);

    // masked V^T + mask-row prep
    {
        dim3 grid(32, 16);
        prep_vt<<<grid, 256, 0, stream>>>(t, wmask, VtG);
    }

    // MFMA flash taylor-attention (2 waves x 32 q-rows)
    {
        dim3 grid(32, 8, 2);
        tmha_attn_mfma<<<grid, 128, 0, stream>>>(Qb, Kb, VtG, attnAb);
    }

    // gemm2: out = attn @ Wo^T  (TM=64 -> 256 blocks = 1/CU)
    {
        dim3 grid(DIM_ / 128, ROWS_ / 64);
        mfma_gemm_bt<64, DIM_, DIM_><<<grid, 256, 0, stream>>>(attnAb, Wob, (float*)d_out);
    }
}

// Round 7
// 200.258 us; speedup vs baseline: 12.9648x; 1.0199x over previous
//
#include <hip/hip_runtime.h>
#include <hip/hip_bf16.h>

// Problem constants
#define B_    2
#define S_    2048
#define DIM_  512
#define H_    8
#define HD_   64
#define TOUT_ 1536   // 2*QK + DIM
#define ROWS_ (B_ * S_)   // 4096

typedef unsigned short ushort_t;
typedef __attribute__((ext_vector_type(8))) __bf16 bf16x8;
typedef __attribute__((ext_vector_type(4))) float floatx4;

#define AS_GLB __attribute__((address_space(1)))
#define AS_LDS __attribute__((address_space(3)))

// ---------- numeric helpers ----------
__device__ __forceinline__ float bf2f(unsigned int u) { return __uint_as_float(u << 16); }
__device__ __forceinline__ unsigned short f2bfu(float f) {
    unsigned u = __float_as_uint(f);
    unsigned r = (u + 0x7fffu + ((u >> 16) & 1u)) >> 16;
    return (unsigned short)r;
}
__device__ __forceinline__ bf16x8 cvt8(const float* p) {
    float4 a = *reinterpret_cast<const float4*>(p);
    float4 b = *reinterpret_cast<const float4*>(p + 4);
    ushort_t o[8] = {f2bfu(a.x), f2bfu(a.y), f2bfu(a.z), f2bfu(a.w),
                     f2bfu(b.x), f2bfu(b.y), f2bfu(b.z), f2bfu(b.w)};
    return *reinterpret_cast<bf16x8*>(o);
}

// ---------- mask classification (proven R1-R6) ----------
__global__ void tmha_detect(const unsigned char* mb, int* flags) {
    __shared__ int s_bf, s_f, s_u8;
    int tid = threadIdx.x;
    if (tid == 0) { s_bf = 0; s_f = 0; s_u8 = 0; }
    __syncthreads();
    int cbf = 0, cf = 0, cu8 = 0;
    for (int i = tid; i < 4096; i += 256) {
        unsigned char v = mb[i];
        if (v == 0x3F || v == 0x80) {
            cf++;
            if ((i & 3) == 1) cbf++;
        } else if (v != 0 && (i & 3) != 0) {
            cu8++;
        }
    }
    atomicAdd(&s_bf, cbf); atomicAdd(&s_f, cf); atomicAdd(&s_u8, cu8);
    __syncthreads();
    if (tid == 0) {
        int mcls;
        if (s_bf > 0)      mcls = 2;
        else if (s_f > 0)  mcls = 3;
        else if (s_u8 > 0) mcls = 0;
        else               mcls = 1;
        flags[1] = mcls;
    }
}

__global__ void tmha_decode_mask(const unsigned char* mb, const int* flags, int* wm) {
    int i = blockIdx.x * 256 + threadIdx.x;
    if (i >= ROWS_) return;
    int cls = flags[1];
    int v;
    if (cls == 0)      v = (mb[i] != 0);
    else if (cls == 1) v = (reinterpret_cast<const int*>(mb)[i] != 0);
    else if (cls == 2) v = ((reinterpret_cast<const unsigned short*>(mb)[i] & 0x7fffu) != 0);
    else               v = ((reinterpret_cast<const unsigned int*>(mb)[i] & 0x7fffffffu) != 0);
    wm[i] = v;
}

// ---------- fp32 -> bf16 cast (vectorized) ----------
__global__ __launch_bounds__(256) void cast_bf16(const float* __restrict__ src,
                                                 ushort_t* __restrict__ dst, int n4) {
    int i = blockIdx.x * 256 + threadIdx.x;
    if (i >= n4) return;
    float4 v = reinterpret_cast<const float4*>(src)[i];
    ushort_t o[4] = {f2bfu(v.x), f2bfu(v.y), f2bfu(v.z), f2bfu(v.w)};
    reinterpret_cast<uint2*>(dst)[i] = *reinterpret_cast<uint2*>(o);
}

// ==================================================================
// MFMA GEMM (proven R5): C[M,N] = A[M,K] @ B[N,K]^T, XOR-swizzled LDS.
// ==================================================================
template <int TM, int N, int K>
__global__ __launch_bounds__(256) void mfma_gemm_bt(const ushort_t* __restrict__ A,
                                                    const ushort_t* __restrict__ Bm,
                                                    float* __restrict__ C) {
    constexpr int FM = TM / 32;
    __shared__ __align__(16) ushort_t As[TM * 64];
    __shared__ __align__(16) ushort_t Bs[128 * 64];
    int tid = threadIdx.x;
    int lane = tid & 63;
    int wv = tid >> 6;
    int wm = wv >> 1, wn = wv & 1;
    int quad = lane >> 4;
    int mrow = lane & 15;
    int bx = blockIdx.x;
    int by = blockIdx.y;

    floatx4 acc[FM][4];
#pragma unroll
    for (int i = 0; i < FM; i++)
#pragma unroll
        for (int j = 0; j < 4; j++) acc[i][j] = (floatx4){0.f, 0.f, 0.f, 0.f};

    for (int k0 = 0; k0 < K; k0 += 64) {
#pragma unroll
        for (int t = 0; t < TM / 32; t++) {
            int p = (wv * (TM / 32) + t) * 64 + lane;
            int row = p >> 3, cp = p & 7;
            int gc = cp ^ (row & 7);
            const ushort_t* ga = A + (size_t)(by * TM + row) * K + k0 + gc * 8;
            __builtin_amdgcn_global_load_lds((const AS_GLB unsigned int*)ga,
                                             (AS_LDS unsigned int*)&As[(size_t)(wv * (TM / 32) + t) * 64 * 8],
                                             16, 0, 0);
        }
#pragma unroll
        for (int t = 0; t < 4; t++) {
            int p = (wv * 4 + t) * 64 + lane;
            int row = p >> 3, cp = p & 7;
            int gc = cp ^ (row & 7);
            const ushort_t* gb = Bm + (size_t)(bx * 128 + row) * K + k0 + gc * 8;
            __builtin_amdgcn_global_load_lds((const AS_GLB unsigned int*)gb,
                                             (AS_LDS unsigned int*)&Bs[(size_t)(wv * 4 + t) * 64 * 8],
                                             16, 0, 0);
        }
        __syncthreads();
#pragma unroll
        for (int ks = 0; ks < 64; ks += 32) {
            int c = (ks >> 3) + quad;
            bf16x8 af[FM], bf[4];
#pragma unroll
            for (int i = 0; i < FM; i++) {
                int row = wm * (TM / 2) + i * 16 + mrow;
                int pos = row * 8 + (c ^ (row & 7));
                af[i] = *reinterpret_cast<const bf16x8*>(&As[pos * 8]);
            }
#pragma unroll
            for (int j = 0; j < 4; j++) {
                int row = wn * 64 + j * 16 + mrow;
                int pos = row * 8 + (c ^ (row & 7));
                bf[j] = *reinterpret_cast<const bf16x8*>(&Bs[pos * 8]);
            }
#pragma unroll
            for (int i = 0; i < FM; i++)
#pragma unroll
                for (int j = 0; j < 4; j++)
                    acc[i][j] = __builtin_amdgcn_mfma_f32_16x16x32_bf16(af[i], bf[j], acc[i][j], 0, 0, 0);
        }
        __syncthreads();
    }

    int col0 = bx * 128 + wn * 64 + mrow;
    int row0 = by * TM + wm * (TM / 2) + quad * 4;
#pragma unroll
    for (int i = 0; i < FM; i++)
#pragma unroll
        for (int j = 0; j < 4; j++)
#pragma unroll
            for (int r = 0; r < 4; r++)
                C[(size_t)(row0 + i * 16 + r) * N + col0 + j * 16] = acc[i][j][r];
}

// ==================================================================
// MFMA rotation (proven R6): per position s, out = in @ R_s^T if mask.
// One wave per s, no LDS, no barrier. Writes Qb/Kb bf16 [bh][s][64].
// ==================================================================
__global__ __launch_bounds__(256) void rot_qk_mfma(const float* __restrict__ t,
                                                   const float* __restrict__ rotG,
                                                   const int* __restrict__ wm,
                                                   ushort_t* __restrict__ Qb,
                                                   ushort_t* __restrict__ Kb) {
    int lane = threadIdx.x & 63;
    int wv = threadIdx.x >> 6;
    int row = blockIdx.x * 4 + wv;     // b*2048 + s
    int b = row >> 11, s = row & 2047;
    int lm = lane & 15, quad = lane >> 4;
    const float* trow = t + (size_t)row * TOUT_;

    if (wm[row]) {
        bf16x8 af[2];
#pragma unroll
        for (int kc = 0; kc < 2; kc++)
            af[kc] = cvt8(trow + lm * 64 + kc * 32 + quad * 8);

        const float* R = rotG + (size_t)row * 4096;
        floatx4 dacc[4];
#pragma unroll
        for (int nb = 0; nb < 4; nb++) dacc[nb] = (floatx4){0.f, 0.f, 0.f, 0.f};
#pragma unroll
        for (int nb = 0; nb < 4; nb++)
#pragma unroll
            for (int kc = 0; kc < 2; kc++) {
                bf16x8 bfr = cvt8(R + (size_t)(nb * 16 + lm) * 64 + kc * 32 + quad * 8);
                dacc[nb] = __builtin_amdgcn_mfma_f32_16x16x32_bf16(af[kc], bfr, dacc[nb], 0, 0, 0);
            }
#pragma unroll
        for (int nb = 0; nb < 4; nb++)
#pragma unroll
            for (int r = 0; r < 4; r++) {
                int vec = quad * 4 + r;
                int h = vec & 7;
                ushort_t* dst = (vec >= 8 ? Kb : Qb);
                dst[((size_t)(b * 8 + h) * 2048 + s) * 64 + nb * 16 + lm] = f2bfu(dacc[nb][r]);
            }
    } else {
#pragma unroll
        for (int nb = 0; nb < 4; nb++)
#pragma unroll
            for (int r = 0; r < 4; r++) {
                int vec = quad * 4 + r;
                int h = vec & 7;
                float v = trow[vec * 64 + nb * 16 + lm];
                ushort_t* dst = (vec >= 8 ? Kb : Qb);
                dst[((size_t)(b * 8 + h) * 2048 + s) * 64 + nb * 16 + lm] = f2bfu(v);
            }
    }
}

// ---------- prep: V^T bf16 [bh][65][2048]; masked keys zeroed; row 64 = mask (proven R4) ----------
__global__ __launch_bounds__(256) void prep_vt(const float* __restrict__ t,
                                               const int* __restrict__ wm,
                                               ushort_t* __restrict__ VtG) {
    __shared__ float tile[64][65];
    __shared__ float mrow[64];
    int st = blockIdx.x;   // 0..31 (64-key tile)
    int bh = blockIdx.y;   // 0..15
    int b = bh >> 3, h = bh & 7;
    int tid = threadIdx.x;
    if (tid < 64) mrow[tid] = wm[b * 2048 + st * 64 + tid] ? 1.0f : 0.0f;
#pragma unroll
    for (int i = 0; i < 4; i++) {
        int q = i * 256 + tid;
        int r = q >> 4, c4 = (q & 15) * 4;
        float4 v = *reinterpret_cast<const float4*>(
            t + (size_t)(b * 2048 + st * 64 + r) * TOUT_ + 1024 + h * 64 + c4);
        tile[r][c4] = v.x; tile[r][c4 + 1] = v.y; tile[r][c4 + 2] = v.z; tile[r][c4 + 3] = v.w;
    }
    __syncthreads();
#pragma unroll
    for (int i = 0; i < 8; i++) {
        int e = i * 256 + tid;
        int d = e >> 5, sl = (e & 31) * 2;
        float v0 = tile[sl][d] * mrow[sl];
        float v1 = tile[sl + 1][d] * mrow[sl + 1];
        unsigned int u = (unsigned)f2bfu(v0) | ((unsigned)f2bfu(v1) << 16);
        *reinterpret_cast<unsigned int*>(VtG + ((size_t)bh * 65 + d) * 2048 + st * 64 + sl) = u;
    }
    if (tid < 32) {
        int sl = tid * 2;
        unsigned m0 = mrow[sl]     != 0.f ? 0x3F80u : 0u;
        unsigned m1 = mrow[sl + 1] != 0.f ? 0x3F80u : 0u;
        *reinterpret_cast<unsigned int*>(VtG + ((size_t)bh * 65 + 64) * 2048 + st * 64 + sl) = m0 | (m1 << 16);
    }
}

// ==================================================================
// MFMA flash taylor-attention, v3: R4-proven inner loop (256 thr = 4
// waves x 16 q-rows) + split-K over keys (ksplit=2). Grid (32,8,4) =
// 1024 blocks, 52 KB LDS -> 3 blocks/CU = 12 waves/CU.
// Each split writes fp32 numer [ks][row][512] and den [ks][row][h].
// ==================================================================
__global__ __launch_bounds__(256) void tmha_attn_mfma(const ushort_t* __restrict__ Qb,
                                                      const ushort_t* __restrict__ Kb,
                                                      const ushort_t* __restrict__ VtG,
                                                      float* __restrict__ numer,
                                                      float* __restrict__ den) {
    __shared__ __align__(16) ushort_t Ks[1024 * 8];   // 128 keys x 8 chunks (16 KB)
    __shared__ __align__(16) ushort_t Vs[1280 * 8];   // 80 dims x 16 chunks (20 KB)
    __shared__ __align__(16) ushort_t Ps[1024 * 8];   // 64 q x 16 chunks (16 KB)
    int tid = threadIdx.x;
    int lane = tid & 63;
    int wv = tid >> 6;
    int lm = lane & 15;
    int quad = lane >> 4;
    int qt = blockIdx.x;
    int h = blockIdx.y;
    int z = blockIdx.z;
    int b = z >> 1;
    int ks = z & 1;
    int bh = b * 8 + h;

    // zero Vs rows 65..79 once
    for (int i = tid; i < 960; i += 256)
        reinterpret_cast<unsigned int*>(&Vs[1040 * 8])[i] = 0u;

    bf16x8 qf[2];
    {
        const ushort_t* qp = Qb + ((size_t)bh * 2048 + qt * 64 + wv * 16 + lm) * 64 + quad * 8;
        qf[0] = *reinterpret_cast<const bf16x8*>(qp);
        qf[1] = *reinterpret_cast<const bf16x8*>(qp + 32);
    }

    floatx4 oacc[5];
#pragma unroll
    for (int j = 0; j < 5; j++) oacc[j] = (floatx4){0.f, 0.f, 0.f, 0.f};

    for (int kt = ks * 1024; kt < ks * 1024 + 1024; kt += 128) {
#pragma unroll
        for (int t4 = 0; t4 < 4; t4++) {
            int p = (wv * 4 + t4) * 64 + lane;
            int row = p >> 3, cp = p & 7;
            int gc = cp ^ (row & 7);
            const ushort_t* g = Kb + ((size_t)bh * 2048 + kt + row) * 64 + gc * 8;
            __builtin_amdgcn_global_load_lds((const AS_GLB unsigned int*)g,
                                             (AS_LDS unsigned int*)&Ks[(size_t)(wv * 4 + t4) * 64 * 8],
                                             16, 0, 0);
        }
#pragma unroll
        for (int t4 = 0; t4 < 4; t4++) {
            int p = (wv * 4 + t4) * 64 + lane;
            int row = p >> 4, cp = p & 15;
            int gc = cp ^ (row & 15);
            const ushort_t* g = VtG + ((size_t)bh * 65 + row) * 2048 + kt + gc * 8;
            __builtin_amdgcn_global_load_lds((const AS_GLB unsigned int*)g,
                                             (AS_LDS unsigned int*)&Vs[(size_t)(wv * 4 + t4) * 64 * 8],
                                             16, 0, 0);
        }
        if (tid < 64) {
            unsigned int mv = *reinterpret_cast<const unsigned int*>(
                VtG + ((size_t)bh * 65 + 64) * 2048 + kt + tid * 2);
            reinterpret_cast<unsigned int*>(&Vs[1024 * 8])[tid] = mv;
        }
        __syncthreads();

        // ---- QK^T: 16 q rows x 128 keys per wave ----
        floatx4 sacc[8];
#pragma unroll
        for (int j = 0; j < 8; j++) sacc[j] = (floatx4){0.f, 0.f, 0.f, 0.f};
#pragma unroll
        for (int j = 0; j < 8; j++) {
            int row = j * 16 + lm;
#pragma unroll
            for (int kc = 0; kc < 2; kc++) {
                int c = kc * 4 + quad;
                int pos = row * 8 + (c ^ (row & 7));
                bf16x8 bk = *reinterpret_cast<const bf16x8*>(&Ks[pos * 8]);
                sacc[j] = __builtin_amdgcn_mfma_f32_16x16x32_bf16(qf[kc], bk, sacc[j], 0, 0, 0);
            }
        }

        // ---- taylor weights -> P (bf16, swizzled) ----
#pragma unroll
        for (int j = 0; j < 8; j++)
#pragma unroll
            for (int r = 0; r < 4; r++) {
                float s = sacc[j][r];
                float wgt = fmaf(s, fmaf(s, 0.0078125f, 0.125f), 1.0f);  // 1 + s/8 + s^2/128
                int m = wv * 16 + quad * 4 + r;
                int col = j * 16 + lm;
                int cw = col >> 3;
                int pos = m * 16 + (cw ^ (m & 15));
                Ps[pos * 8 + (col & 7)] = f2bfu(wgt);
            }
        __syncthreads();

        // ---- P @ V': O[16 q][80] (col 64 = denominator) ----
#pragma unroll
        for (int j = 0; j < 5; j++) {
            int vrow = j * 16 + lm;
#pragma unroll
            for (int kc = 0; kc < 4; kc++) {
                int c = kc * 4 + quad;
                int ppos = (wv * 16 + lm) * 16 + (c ^ lm);
                bf16x8 pa = *reinterpret_cast<const bf16x8*>(&Ps[ppos * 8]);
                int vpos = vrow * 16 + (c ^ (vrow & 15));
                bf16x8 vb = *reinterpret_cast<const bf16x8*>(&Vs[vpos * 8]);
                oacc[j] = __builtin_amdgcn_mfma_f32_16x16x32_bf16(pa, vb, oacc[j], 0, 0, 0);
            }
        }
        __syncthreads();
    }

    // ---- epilogue: write split numerator + denominator (fp32) ----
#pragma unroll
    for (int j = 0; j < 4; j++)
#pragma unroll
        for (int r = 0; r < 4; r++) {
            int qrow = b * 2048 + qt * 64 + wv * 16 + quad * 4 + r;
            numer[((size_t)ks * ROWS_ + qrow) * DIM_ + h * 64 + j * 16 + lm] = oacc[j][r];
        }
    if (lm == 0) {
#pragma unroll
        for (int r = 0; r < 4; r++) {
            int qrow = b * 2048 + qt * 64 + wv * 16 + quad * 4 + r;
            den[((size_t)ks * ROWS_ + qrow) * 8 + h] = oacc[4][r];
        }
    }
}

// ---------- combine splits: attn = (n0+n1)/(d0+d1), bf16 ----------
__global__ __launch_bounds__(256) void attn_combine(const float* __restrict__ numer,
                                                    const float* __restrict__ den,
                                                    ushort_t* __restrict__ attnAb) {
    int i = blockIdx.x * 256 + threadIdx.x;      // over 4096*128 float4s
    int row = i >> 7;
    int c4 = (i & 127) * 4;
    int h = c4 >> 6;
    float4 n0 = *reinterpret_cast<const float4*>(&numer[(size_t)row * DIM_ + c4]);
    float4 n1 = *reinterpret_cast<const float4*>(&numer[((size_t)ROWS_ + row) * DIM_ + c4]);
    float d = den[(size_t)row * 8 + h] + den[((size_t)ROWS_ + row) * 8 + h];
    float inv = 1.0f / d;
    ushort_t o[4] = {f2bfu((n0.x + n1.x) * inv), f2bfu((n0.y + n1.y) * inv),
                     f2bfu((n0.z + n1.z) * inv), f2bfu((n0.w + n1.w) * inv)};
    *reinterpret_cast<uint2*>(&attnAb[(size_t)row * DIM_ + c4]) = *reinterpret_cast<uint2*>(o);
}

extern "C" void kernel_launch(void* const* d_in, const int* in_sizes, int n_in,
                              void* d_out, int out_size, void* d_ws, size_t ws_size,
                              hipStream_t stream) {
    (void)in_sizes; (void)n_in; (void)out_size; (void)ws_size;
    const float* x    = (const float*)d_in[0];
    const void*  mask = d_in[1];
    const float* rot  = (const float*)d_in[2];
    const float* Wt   = (const float*)d_in[3];
    const float* Wo   = (const float*)d_in[4];

    char* ws = (char*)d_ws;
    int* flags       = (int*)ws;                            // 64 B
    int* wmask       = (int*)(ws + 64);                     // 16 KB
    float* t         = (float*)(ws + 32768);                // 25,165,824 B
    ushort_t* Xb     = (ushort_t*)(ws + 25198592);          //  4,194,304 B
    ushort_t* Wtb    = (ushort_t*)(ws + 29392896);          //  1,572,864 B
    ushort_t* Wob    = (ushort_t*)(ws + 30965760);          //    524,288 B
    ushort_t* Qb     = (ushort_t*)(ws + 31490048);          //  4,194,304 B
    ushort_t* Kb     = (ushort_t*)(ws + 35684352);          //  4,194,304 B
    ushort_t* VtG    = (ushort_t*)(ws + 39878656);          //  4,259,840 B
    ushort_t* attnAb = (ushort_t*)(ws + 44138496);          //  4,194,304 B -> ends 48,332,800
    // split-K attention outputs reuse t's space (t is dead after prep_vt)
    float* numer     = t;                                   // 2 * 4096 * 512 * 4 = 16,777,216 B
    float* den       = (float*)(ws + 32768 + 16777216);     // 2 * 4096 * 8 * 4 = 262,144 B

    tmha_detect<<<1, 256, 0, stream>>>((const unsigned char*)mask, flags);
    tmha_decode_mask<<<16, 256, 0, stream>>>((const unsigned char*)mask, flags, wmask);

    // bf16 casts
    cast_bf16<<<(ROWS_ * DIM_ / 4 + 255) / 256, 256, 0, stream>>>(x, Xb, ROWS_ * DIM_ / 4);
    cast_bf16<<<(TOUT_ * DIM_ / 4 + 255) / 256, 256, 0, stream>>>(Wt, Wtb, TOUT_ * DIM_ / 4);
    cast_bf16<<<(DIM_ * DIM_ / 4 + 255) / 256, 256, 0, stream>>>(Wo, Wob, DIM_ * DIM_ / 4);

    // gemm1: t = x @ Wt^T  (TM=64 -> 768 blocks = 3/CU)
    {
        dim3 grid(TOUT_ / 128, ROWS_ / 64);
        mfma_gemm_bt<64, TOUT_, DIM_><<<grid, 256, 0, stream>>>(Xb, Wtb, t);
    }

    // MFMA rotation + q/k bf16 pack (1 wave per position, no LDS)
    rot_qk_mfma<<<ROWS_ / 4, 256, 0, stream>>>(t, rot, wmask, Qb, Kb);

    // masked V^T + mask-row prep
    {
        dim3 grid(32, 16);
        prep_vt<<<grid, 256, 0, stream>>>(t, wmask, VtG);
    }

    // MFMA flash taylor-attention, split-K (ksplit=2): 1024 blocks, 3/CU
    {
        dim3 grid(32, 8, 4);
        tmha_attn_mfma<<<grid, 256, 0, stream>>>(Qb, Kb, VtG, numer, den);
    }
    attn_combine<<<(ROWS_ * 128) / 256, 256, 0, stream>>>(numer, den, attnAb);

    // gemm2: out = attn @ Wo^T  (TM=64 -> 256 blocks = 1/CU)
    {
        dim3 grid(DIM_ / 128, ROWS_ / 64);
        mfma_gemm_bt<64, DIM_, DIM_><<<grid, 256, 0, stream>>>(attnAb, Wob, (float*)d_out);
    }
}